// Round 1
// baseline (4320.436 us; speedup 1.0000x reference)
//
#include <hip/hip_runtime.h>

typedef __attribute__((ext_vector_type(8))) short bf16x8;
typedef __attribute__((ext_vector_type(4))) float f32x4;

static __device__ __forceinline__ short f2bf(float f) {
  union { float f; unsigned u; } v; v.f = f;
  unsigned r = v.u + 0x7fffu + ((v.u >> 16) & 1u);
  return (short)(r >> 16);
}

#define GLOBAL_AS(p) ((const __attribute__((address_space(1))) void*)(p))
#define LDS_AS(p)    ((__attribute__((address_space(3))) void*)(p))

// ---------------------------------------------------------------------------
// Weight fp32 -> bf16 transposed: Wt[n*ldt + koff + k] = bf16(W[k*N + n])
// grid: (K/32, N/32), block: 256
__global__ void wconv_kernel(const float* __restrict__ W, short* __restrict__ Wt,
                             int K, int N, int ldt, int koff) {
  __shared__ float tile[32][33];
  int kb = blockIdx.x * 32, nb = blockIdx.y * 32;
  int tx = threadIdx.x & 31, ty = threadIdx.x >> 5;   // ty 0..7
#pragma unroll
  for (int j = 0; j < 4; ++j) {
    int k = kb + ty + 8 * j;
    tile[ty + 8 * j][tx] = W[(size_t)k * N + nb + tx];
  }
  __syncthreads();
#pragma unroll
  for (int j = 0; j < 4; ++j) {
    int n = nb + ty + 8 * j;
    Wt[(size_t)n * ldt + koff + kb + tx] = f2bf(tile[tx][ty + 8 * j]);
  }
}

// ---------------------------------------------------------------------------
// Segment-sum scatter: 2 edges per 256-thread block, 128 threads/edge, float4.
__global__ void scatter_kernel(const float* __restrict__ xall, const int* __restrict__ ei,
                               int E, float* __restrict__ ssum, float* __restrict__ cnt) {
  int e = blockIdx.x * 2 + (threadIdx.x >> 7);
  if (e >= E) return;
  int src = ei[e];
  int dst = ei[E + e];
  int c = (threadIdx.x & 127) * 4;
  float4 v = *(const float4*)(xall + (size_t)src * 512 + c);
  float* d = ssum + (size_t)dst * 512 + c;
  atomicAdd(d + 0, v.x);
  atomicAdd(d + 1, v.y);
  atomicAdd(d + 2, v.z);
  atomicAdd(d + 3, v.w);
  if ((threadIdx.x & 127) == 0) atomicAdd(cnt + dst, 1.0f);
}

// ---------------------------------------------------------------------------
// Build A = [mean | x_dst] as bf16, row stride 1024. grid: n_dst, block: 256
__global__ void build_a_kernel(const float* __restrict__ ssum, const float* __restrict__ cnt,
                               const float* __restrict__ xall, short* __restrict__ A, int n_dst) {
  int i = blockIdx.x;
  int c = threadIdx.x * 4;
  float4 v;
  if (c < 512) {
    float inv = 1.0f / fmaxf(cnt[i], 1.0f);
    v = *(const float4*)(ssum + (size_t)i * 512 + c);
    v.x *= inv; v.y *= inv; v.z *= inv; v.w *= inv;
  } else {
    v = *(const float4*)(xall + (size_t)i * 512 + (c - 512));
  }
  short4 o;
  o.x = f2bf(v.x); o.y = f2bf(v.y); o.z = f2bf(v.z); o.w = f2bf(v.w);
  *(short4*)(A + (size_t)i * 1024 + c) = o;
}

// ---------------------------------------------------------------------------
// bf16 MFMA GEMM: C(MxN) = A(MxK, row-major bf16, stride lda) @ Bt^T
// (Bt is N x K bf16, stride ldb) [+ bias]. 128x128 tile, BK=32, 256 thr.
__global__ __launch_bounds__(256, 2)
void gemm_kernel(const short* __restrict__ A, int lda,
                 const short* __restrict__ Bt, int ldb,
                 float* __restrict__ C, int ldc,
                 int M, int N, int K, const float* __restrict__ bias) {
  __shared__ short lds[8192];
  short* As = lds;          // [128][32]
  short* Bs = lds + 4096;   // [128][32]
  const int tid = threadIdx.x;
  const int wid = tid >> 6;
  const int lane = tid & 63;
  const int lm = lane & 15;
  const int quad = lane >> 4;
  const int wr = wid >> 1, wc = wid & 1;
  const int bm = blockIdx.x, bn = blockIdx.y;
  const int lrow = lane >> 2;        // 0..15
  const int lkb = (lane & 3) * 8;    // k offset (elements)

  f32x4 acc[4][4];
#pragma unroll
  for (int i = 0; i < 4; ++i)
#pragma unroll
    for (int j = 0; j < 4; ++j) acc[i][j] = (f32x4)0.f;

  for (int k0 = 0; k0 < K; k0 += 32) {
#pragma unroll
    for (int j = 0; j < 2; ++j) {
      int ch = wid * 2 + j;
      int arow = bm * 128 + ch * 16 + lrow;
      arow = arow < M ? arow : M - 1;
      const short* ga = A + (size_t)arow * lda + k0 + lkb;
      __builtin_amdgcn_global_load_lds(GLOBAL_AS(ga), LDS_AS(As + ch * 512), 16, 0, 0);
      int brow = bn * 128 + ch * 16 + lrow;
      const short* gb = Bt + (size_t)brow * ldb + k0 + lkb;
      __builtin_amdgcn_global_load_lds(GLOBAL_AS(gb), LDS_AS(Bs + ch * 512), 16, 0, 0);
    }
    __syncthreads();
    bf16x8 af[4], bfr[4];
#pragma unroll
    for (int mi = 0; mi < 4; ++mi)
      af[mi] = *(const bf16x8*)(As + (wr * 64 + mi * 16 + lm) * 32 + quad * 8);
#pragma unroll
    for (int ni = 0; ni < 4; ++ni)
      bfr[ni] = *(const bf16x8*)(Bs + (wc * 64 + ni * 16 + lm) * 32 + quad * 8);
#pragma unroll
    for (int mi = 0; mi < 4; ++mi)
#pragma unroll
      for (int ni = 0; ni < 4; ++ni)
        acc[mi][ni] = __builtin_amdgcn_mfma_f32_16x16x32_bf16(af[mi], bfr[ni], acc[mi][ni], 0, 0, 0);
    __syncthreads();
  }

#pragma unroll
  for (int mi = 0; mi < 4; ++mi) {
#pragma unroll
    for (int ni = 0; ni < 4; ++ni) {
      int gcol = bn * 128 + wc * 64 + ni * 16 + lm;
      float bv = bias ? bias[gcol] : 0.f;
#pragma unroll
      for (int r2 = 0; r2 < 4; ++r2) {
        int grow = bm * 128 + wr * 64 + mi * 16 + quad * 4 + r2;
        if (grow < M) C[(size_t)grow * ldc + gcol] = acc[mi][ni][r2] + bv;
      }
    }
  }
}

// ---------------------------------------------------------------------------
// Column sums of h and h^2 into stats[0:512] and stats[512:1024].
// grid: ceil(n/128), block 256 (2 cols/thread)
__global__ void colstats_kernel(const float* __restrict__ h, int n, float* __restrict__ stats) {
  int c = threadIdx.x;
  int r0 = blockIdx.x * 128;
  int r1 = min(r0 + 128, n);
  float s1a = 0.f, s2a = 0.f, s1b = 0.f, s2b = 0.f;
  for (int r = r0; r < r1; ++r) {
    float a = h[(size_t)r * 512 + c];
    float b = h[(size_t)r * 512 + c + 256];
    s1a += a; s2a += a * a;
    s1b += b; s2b += b * b;
  }
  atomicAdd(&stats[c], s1a);
  atomicAdd(&stats[512 + c], s2a);
  atomicAdd(&stats[c + 256], s1b);
  atomicAdd(&stats[512 + c + 256], s2b);
}

// stats[1024:1536] = mu, stats[1536:2048] = rstd. grid 2, block 256.
__global__ void bnfin_kernel(float* __restrict__ stats, float inv_n) {
  int c = blockIdx.x * 256 + threadIdx.x;
  float mu = stats[c] * inv_n;
  float var = stats[512 + c] * inv_n - mu * mu;
  stats[1024 + c] = mu;
  stats[1536 + c] = rsqrtf(var + 1e-5f);
}

// ---------------------------------------------------------------------------
// x_out = leaky(BN(h)) + (r + res_b)  or  + xdst. grid n, block 128, float4.
__global__ void apply_kernel(const float* __restrict__ h, const float* __restrict__ stats,
                             const float* __restrict__ g, const float* __restrict__ b,
                             const float* __restrict__ r, const float* __restrict__ res_b,
                             const float* __restrict__ xdst, float* __restrict__ outp, int n) {
  int i = blockIdx.x;
  int c = threadIdx.x * 4;
  float4 hv = *(const float4*)(h + (size_t)i * 512 + c);
  float4 mu = *(const float4*)(stats + 1024 + c);
  float4 rs = *(const float4*)(stats + 1536 + c);
  float4 gv = *(const float4*)(g + c);
  float4 bv = *(const float4*)(b + c);
  float4 o;
  o.x = (hv.x - mu.x) * rs.x * gv.x + bv.x;
  o.y = (hv.y - mu.y) * rs.y * gv.y + bv.y;
  o.z = (hv.z - mu.z) * rs.z * gv.z + bv.z;
  o.w = (hv.w - mu.w) * rs.w * gv.w + bv.w;
  o.x = o.x >= 0.f ? o.x : 0.01f * o.x;
  o.y = o.y >= 0.f ? o.y : 0.01f * o.y;
  o.z = o.z >= 0.f ? o.z : 0.01f * o.z;
  o.w = o.w >= 0.f ? o.w : 0.01f * o.w;
  if (r) {
    float4 rv = *(const float4*)(r + (size_t)i * 512 + c);
    float4 rb = *(const float4*)(res_b + c);
    o.x += rv.x + rb.x; o.y += rv.y + rb.y; o.z += rv.z + rb.z; o.w += rv.w + rb.w;
  } else {
    float4 xv = *(const float4*)(xdst + (size_t)i * 512 + c);
    o.x += xv.x; o.y += xv.y; o.z += xv.z; o.w += xv.w;
  }
  *(float4*)(outp + (size_t)i * 512 + c) = o;
}

// ---------------------------------------------------------------------------
// feat (8000 x 2048 bf16) = concat(x0,x1,x2,x3)[:8000]. grid 8000, block 256.
__global__ void feat_kernel(const float* __restrict__ x0, const float* __restrict__ x1,
                            const float* __restrict__ x2, const float* __restrict__ x3,
                            short* __restrict__ feat) {
  int i = blockIdx.x, t = threadIdx.x;
  int c = t * 8;
  int sel = c >> 9;
  const float* s = sel == 0 ? x0 : sel == 1 ? x1 : sel == 2 ? x2 : x3;
  int lc = c & 511;
  float4 a = *(const float4*)(s + (size_t)i * 512 + lc);
  float4 b = *(const float4*)(s + (size_t)i * 512 + lc + 4);
  short* d = feat + (size_t)i * 2048 + c;
  short4 o1; o1.x = f2bf(a.x); o1.y = f2bf(a.y); o1.z = f2bf(a.z); o1.w = f2bf(a.w);
  short4 o2; o2.x = f2bf(b.x); o2.y = f2bf(b.y); o2.z = f2bf(b.z); o2.w = f2bf(b.w);
  *(short4*)d = o1;
  *(short4*)(d + 4) = o2;
}

__global__ void tobf16_kernel(const float* __restrict__ in, short* __restrict__ outp, int n4) {
  int i = blockIdx.x * 256 + threadIdx.x;
  if (i < n4) {
    float4 v = ((const float4*)in)[i];
    short4 o; o.x = f2bf(v.x); o.y = f2bf(v.y); o.z = f2bf(v.z); o.w = f2bf(v.w);
    ((short4*)outp)[i] = o;
  }
}

// ---------------------------------------------------------------------------
// log_softmax over 256 cols; one block (256 thr) per row.
__global__ void lsm_kernel(const float* __restrict__ z, float* __restrict__ outp) {
  __shared__ float redm[4], reds[4];
  int row = blockIdx.x, t = threadIdx.x;
  float v = z[(size_t)row * 256 + t];
  float m = v;
#pragma unroll
  for (int o = 32; o >= 1; o >>= 1) m = fmaxf(m, __shfl_down(m, o, 64));
  if ((t & 63) == 0) redm[t >> 6] = m;
  __syncthreads();
  m = fmaxf(fmaxf(redm[0], redm[1]), fmaxf(redm[2], redm[3]));
  float e = __expf(v - m);
  float s = e;
#pragma unroll
  for (int o = 32; o >= 1; o >>= 1) s += __shfl_down(s, o, 64);
  if ((t & 63) == 0) reds[t >> 6] = s;
  __syncthreads();
  s = reds[0] + reds[1] + reds[2] + reds[3];
  outp[(size_t)row * 256 + t] = v - m - __logf(s);
}

// ---------------------------------------------------------------------------
extern "C" void kernel_launch(void* const* d_in, const int* in_sizes, int n_in,
                              void* d_out, int out_size, void* d_ws, size_t ws_size,
                              hipStream_t stream) {
  const float* x0 = (const float*)d_in[0];
  const int* eis[3] = {(const int*)d_in[1], (const int*)d_in[2], (const int*)d_in[3]};
  const float* Wl[3] = {(const float*)d_in[4], (const float*)d_in[8], (const float*)d_in[12]};
  const float* Wr[3] = {(const float*)d_in[5], (const float*)d_in[9], (const float*)d_in[13]};
  const float* gg[3] = {(const float*)d_in[6], (const float*)d_in[10], (const float*)d_in[14]};
  const float* bb[3] = {(const float*)d_in[7], (const float*)d_in[11], (const float*)d_in[15]};
  const float* res_W = (const float*)d_in[16];
  const float* res_b = (const float*)d_in[17];
  const float* mlp_W1 = (const float*)d_in[18];
  const float* mlp_b1 = (const float*)d_in[19];
  const float* mlp_W2 = (const float*)d_in[20];
  const float* mlp_b2 = (const float*)d_in[21];
  float* out = (float*)d_out;

  const int Ns[4] = {60000, 30000, 15000, 8000};
  const int Es[3] = {300000, 150000, 80000};

  char* ws = (char*)d_ws;
  size_t off = 0;
  auto alloc = [&](size_t bytes) { size_t r = off; off += (bytes + 255) & ~(size_t)255; return r; };
  short* Bt[3];
  Bt[0] = (short*)(ws + alloc(512 * 1024 * 2));
  Bt[1] = (short*)(ws + alloc(512 * 1024 * 2));
  Bt[2] = (short*)(ws + alloc(512 * 1024 * 2));
  short* Rt = (short*)(ws + alloc(512 * 512 * 2));
  short* W1t = (short*)(ws + alloc(512 * 2048 * 2));
  short* W2t = (short*)(ws + alloc(256 * 512 * 2));
  float* cnt = (float*)(ws + alloc(30000 * 4));
  float* stats = (float*)(ws + alloc(2048 * 4));
  size_t ssum_off = alloc((size_t)30000 * 512 * 4);
  float* ssum = (float*)(ws + ssum_off);
  short* Abuf = (short*)(ws + alloc((size_t)30000 * 1024 * 2));
  size_t h_off = alloc((size_t)30000 * 512 * 4);
  float* h = (float*)(ws + h_off);
  float* x1 = (float*)(ws + alloc((size_t)30000 * 512 * 4));
  float* x2 = (float*)(ws + alloc((size_t)15000 * 512 * 4));
  float* x3 = (float*)(ws + alloc((size_t)8000 * 512 * 4));
  // overlays (regions free by the time these are used)
  float* rbuf = ssum;                              // layer-1 residual GEMM out
  short* featb = (short*)(ws + h_off);             // 8000x2048 bf16
  float* z1 = (float*)(ws + ssum_off);             // 8000x512 f32
  short* z1b = (short*)(ws + ssum_off + 16777216); // 8000x512 bf16
  float* z2 = (float*)(ws + ssum_off + 16777216 + 8388608); // 8000x256 f32

  // ---- weight prep (transpose + bf16) ----
  wconv_kernel<<<dim3(16, 16), 256, 0, stream>>>(Wl[0], Bt[0], 512, 512, 1024, 0);
  wconv_kernel<<<dim3(16, 16), 256, 0, stream>>>(Wr[0], Bt[0], 512, 512, 1024, 512);
  wconv_kernel<<<dim3(16, 16), 256, 0, stream>>>(Wl[1], Bt[1], 512, 512, 1024, 0);
  wconv_kernel<<<dim3(16, 16), 256, 0, stream>>>(Wr[1], Bt[1], 512, 512, 1024, 512);
  wconv_kernel<<<dim3(16, 16), 256, 0, stream>>>(Wl[2], Bt[2], 512, 512, 1024, 0);
  wconv_kernel<<<dim3(16, 16), 256, 0, stream>>>(Wr[2], Bt[2], 512, 512, 1024, 512);
  wconv_kernel<<<dim3(16, 16), 256, 0, stream>>>(res_W, Rt, 512, 512, 512, 0);
  wconv_kernel<<<dim3(64, 16), 256, 0, stream>>>(mlp_W1, W1t, 2048, 512, 2048, 0);
  wconv_kernel<<<dim3(16, 8), 256, 0, stream>>>(mlp_W2, W2t, 512, 256, 512, 0);

  const float* xin[3] = {x0, x1, x2};
  float* xout[3] = {x1, x2, x3};

  for (int l = 0; l < 3; ++l) {
    int n_dst = Ns[l + 1];
    int E = Es[l];
    hipMemsetAsync(ssum, 0, (size_t)n_dst * 512 * 4, stream);
    hipMemsetAsync(cnt, 0, (size_t)n_dst * 4, stream);
    scatter_kernel<<<dim3((E + 1) / 2), 256, 0, stream>>>(xin[l], eis[l], E, ssum, cnt);
    build_a_kernel<<<dim3(n_dst), 256, 0, stream>>>(ssum, cnt, xin[l], Abuf, n_dst);
    int gm = (n_dst + 127) / 128;
    gemm_kernel<<<dim3(gm, 4), 256, 0, stream>>>(Abuf, 1024, Bt[l], 1024, h, 512,
                                                 n_dst, 512, 1024, nullptr);
    if (l == 0)
      gemm_kernel<<<dim3(gm, 4), 256, 0, stream>>>(Abuf + 512, 1024, Rt, 512, rbuf, 512,
                                                   n_dst, 512, 512, nullptr);
    hipMemsetAsync(stats, 0, 1024 * 4, stream);
    colstats_kernel<<<dim3((n_dst + 127) / 128), 256, 0, stream>>>(h, n_dst, stats);
    bnfin_kernel<<<dim3(2), 256, 0, stream>>>(stats, 1.0f / n_dst);
    apply_kernel<<<dim3(n_dst), 128, 0, stream>>>(h, stats, gg[l], bb[l],
                                                  l == 0 ? rbuf : nullptr, res_b,
                                                  xin[l], xout[l], n_dst);
  }

  // ---- head ----
  feat_kernel<<<dim3(8000), 256, 0, stream>>>(x0, x1, x2, x3, featb);
  gemm_kernel<<<dim3(63, 4), 256, 0, stream>>>(featb, 2048, W1t, 2048, z1, 512,
                                               8000, 512, 2048, mlp_b1);
  tobf16_kernel<<<dim3(4000), 256, 0, stream>>>(z1, z1b, 8000 * 512 / 4);
  gemm_kernel<<<dim3(63, 2), 256, 0, stream>>>(z1b, 512, W2t, 512, z2, 256,
                                               8000, 256, 512, mlp_b2);
  lsm_kernel<<<dim3(8000), 256, 0, stream>>>(z2, out);
}

// Round 2
// 1031.024 us; speedup vs baseline: 4.1904x; 4.1904x over previous
//
#include <hip/hip_runtime.h>

typedef __attribute__((ext_vector_type(8))) short bf16x8;
typedef __attribute__((ext_vector_type(4))) float f32x4;

static __device__ __forceinline__ short f2bf(float f) {
  union { float f; unsigned u; } v; v.f = f;
  unsigned r = v.u + 0x7fffu + ((v.u >> 16) & 1u);
  return (short)(r >> 16);
}

#define GLOBAL_AS(p) ((const __attribute__((address_space(1))) void*)(p))
#define LDS_AS(p)    ((__attribute__((address_space(3))) void*)(p))

// ---------------------------------------------------------------------------
// Weight fp32 -> bf16 transposed: Wt[n*ldt + koff + k] = bf16(W[k*N + n])
__global__ void wconv_kernel(const float* __restrict__ W, short* __restrict__ Wt,
                             int K, int N, int ldt, int koff) {
  __shared__ float tile[32][33];
  int kb = blockIdx.x * 32, nb = blockIdx.y * 32;
  int tx = threadIdx.x & 31, ty = threadIdx.x >> 5;
#pragma unroll
  for (int j = 0; j < 4; ++j) {
    int k = kb + ty + 8 * j;
    tile[ty + 8 * j][tx] = W[(size_t)k * N + nb + tx];
  }
  __syncthreads();
#pragma unroll
  for (int j = 0; j < 4; ++j) {
    int n = nb + ty + 8 * j;
    Wt[(size_t)n * ldt + koff + kb + tx] = f2bf(tile[tx][ty + 8 * j]);
  }
}

// ---------------------------------------------------------------------------
// CSR build: degree histogram, single-block scan, fill.
__global__ void deg_kernel(const int* __restrict__ ei, int E, int* __restrict__ deg) {
  int e = blockIdx.x * 256 + threadIdx.x;
  if (e < E) atomicAdd(&deg[ei[E + e]], 1);
}

__global__ void scan_kernel(const int* __restrict__ deg, int* __restrict__ offs, int n) {
  __shared__ int sums[257];
  int t = threadIdx.x;
  int per = (n + 255) / 256;
  int b = t * per, e = min(b + per, n);
  int s = 0;
  for (int i = b; i < e; ++i) s += deg[i];
  sums[t] = s;
  __syncthreads();
  if (t == 0) {
    int acc = 0;
    for (int i = 0; i < 256; ++i) { int v = sums[i]; sums[i] = acc; acc += v; }
    sums[256] = acc;
  }
  __syncthreads();
  int acc = sums[t];
  for (int i = b; i < e; ++i) { offs[i] = acc; acc += deg[i]; }
  if (t == 255) offs[n] = sums[256];
}

__global__ void fill_kernel(const int* __restrict__ ei, int E, const int* __restrict__ offs,
                            int* __restrict__ cursor, int* __restrict__ csr) {
  int e = blockIdx.x * 256 + threadIdx.x;
  if (e < E) {
    int d = ei[E + e];
    int p = atomicAdd(&cursor[d], 1);
    csr[offs[d] + p] = ei[e];
  }
}

// ---------------------------------------------------------------------------
// Gather aggregation + fused A build: A[i] = [bf16(mean_{src in N(i)} x[src]) | bf16(x[i])]
// grid: n_dst, block: 256 (float2 per thread).
__global__ void aggregate_kernel(const float* __restrict__ x, const int* __restrict__ csr,
                                 const int* __restrict__ offs, short* __restrict__ A,
                                 int n_dst) {
  int i = blockIdx.x;
  int t = threadIdx.x;
  int s0 = offs[i], s1 = offs[i + 1];
  float ax = 0.f, ay = 0.f;
  const float* xp = x + t * 2;
  int e = s0;
  for (; e + 1 < s1; e += 2) {
    int sa = csr[e], sb = csr[e + 1];
    float2 va = *(const float2*)(xp + (size_t)sa * 512);
    float2 vb = *(const float2*)(xp + (size_t)sb * 512);
    ax += va.x + vb.x;
    ay += va.y + vb.y;
  }
  if (e < s1) {
    float2 va = *(const float2*)(xp + (size_t)csr[e] * 512);
    ax += va.x; ay += va.y;
  }
  float inv = (s1 > s0) ? 1.0f / (float)(s1 - s0) : 0.0f;
  short2 o;
  o.x = f2bf(ax * inv); o.y = f2bf(ay * inv);
  *(short2*)(A + (size_t)i * 1024 + t * 2) = o;
  float2 xd = *(const float2*)(xp + (size_t)i * 512);
  short2 o2; o2.x = f2bf(xd.x); o2.y = f2bf(xd.y);
  *(short2*)(A + (size_t)i * 1024 + 512 + t * 2) = o2;
}

// ---------------------------------------------------------------------------
// bf16 MFMA GEMM: C(MxN) = A(MxK bf16, stride lda) @ Bt^T (Bt: NxK bf16) [+bias]
__global__ __launch_bounds__(256, 2)
void gemm_kernel(const short* __restrict__ A, int lda,
                 const short* __restrict__ Bt, int ldb,
                 float* __restrict__ C, int ldc,
                 int M, int N, int K, const float* __restrict__ bias) {
  __shared__ short lds[8192];
  short* As = lds;
  short* Bs = lds + 4096;
  const int tid = threadIdx.x;
  const int wid = tid >> 6;
  const int lane = tid & 63;
  const int lm = lane & 15;
  const int quad = lane >> 4;
  const int wr = wid >> 1, wc = wid & 1;
  const int bm = blockIdx.x, bn = blockIdx.y;
  const int lrow = lane >> 2;
  const int lkb = (lane & 3) * 8;

  f32x4 acc[4][4];
#pragma unroll
  for (int i = 0; i < 4; ++i)
#pragma unroll
    for (int j = 0; j < 4; ++j) acc[i][j] = (f32x4)0.f;

  for (int k0 = 0; k0 < K; k0 += 32) {
#pragma unroll
    for (int j = 0; j < 2; ++j) {
      int ch = wid * 2 + j;
      int arow = bm * 128 + ch * 16 + lrow;
      arow = arow < M ? arow : M - 1;
      const short* ga = A + (size_t)arow * lda + k0 + lkb;
      __builtin_amdgcn_global_load_lds(GLOBAL_AS(ga), LDS_AS(As + ch * 512), 16, 0, 0);
      int brow = bn * 128 + ch * 16 + lrow;
      const short* gb = Bt + (size_t)brow * ldb + k0 + lkb;
      __builtin_amdgcn_global_load_lds(GLOBAL_AS(gb), LDS_AS(Bs + ch * 512), 16, 0, 0);
    }
    __syncthreads();
    bf16x8 af[4], bfr[4];
#pragma unroll
    for (int mi = 0; mi < 4; ++mi)
      af[mi] = *(const bf16x8*)(As + (wr * 64 + mi * 16 + lm) * 32 + quad * 8);
#pragma unroll
    for (int ni = 0; ni < 4; ++ni)
      bfr[ni] = *(const bf16x8*)(Bs + (wc * 64 + ni * 16 + lm) * 32 + quad * 8);
#pragma unroll
    for (int mi = 0; mi < 4; ++mi)
#pragma unroll
      for (int ni = 0; ni < 4; ++ni)
        acc[mi][ni] = __builtin_amdgcn_mfma_f32_16x16x32_bf16(af[mi], bfr[ni], acc[mi][ni], 0, 0, 0);
    __syncthreads();
  }

#pragma unroll
  for (int mi = 0; mi < 4; ++mi) {
#pragma unroll
    for (int ni = 0; ni < 4; ++ni) {
      int gcol = bn * 128 + wc * 64 + ni * 16 + lm;
      float bv = bias ? bias[gcol] : 0.f;
#pragma unroll
      for (int r2 = 0; r2 < 4; ++r2) {
        int grow = bm * 128 + wr * 64 + mi * 16 + quad * 4 + r2;
        if (grow < M) C[(size_t)grow * ldc + gcol] = acc[mi][ni][r2] + bv;
      }
    }
  }
}

// ---------------------------------------------------------------------------
__global__ void colstats_kernel(const float* __restrict__ h, int n, float* __restrict__ stats) {
  int c = threadIdx.x;
  int r0 = blockIdx.x * 128;
  int r1 = min(r0 + 128, n);
  float s1a = 0.f, s2a = 0.f, s1b = 0.f, s2b = 0.f;
  for (int r = r0; r < r1; ++r) {
    float a = h[(size_t)r * 512 + c];
    float b = h[(size_t)r * 512 + c + 256];
    s1a += a; s2a += a * a;
    s1b += b; s2b += b * b;
  }
  atomicAdd(&stats[c], s1a);
  atomicAdd(&stats[512 + c], s2a);
  atomicAdd(&stats[c + 256], s1b);
  atomicAdd(&stats[512 + c + 256], s2b);
}

__global__ void bnfin_kernel(float* __restrict__ stats, float inv_n) {
  int c = blockIdx.x * 256 + threadIdx.x;
  float mu = stats[c] * inv_n;
  float var = stats[512 + c] * inv_n - mu * mu;
  stats[1024 + c] = mu;
  stats[1536 + c] = rsqrtf(var + 1e-5f);
}

// ---------------------------------------------------------------------------
__global__ void apply_kernel(const float* __restrict__ h, const float* __restrict__ stats,
                             const float* __restrict__ g, const float* __restrict__ b,
                             const float* __restrict__ r, const float* __restrict__ res_b,
                             const float* __restrict__ xdst, float* __restrict__ outp, int n) {
  int i = blockIdx.x;
  int c = threadIdx.x * 4;
  float4 hv = *(const float4*)(h + (size_t)i * 512 + c);
  float4 mu = *(const float4*)(stats + 1024 + c);
  float4 rs = *(const float4*)(stats + 1536 + c);
  float4 gv = *(const float4*)(g + c);
  float4 bv = *(const float4*)(b + c);
  float4 o;
  o.x = (hv.x - mu.x) * rs.x * gv.x + bv.x;
  o.y = (hv.y - mu.y) * rs.y * gv.y + bv.y;
  o.z = (hv.z - mu.z) * rs.z * gv.z + bv.z;
  o.w = (hv.w - mu.w) * rs.w * gv.w + bv.w;
  o.x = o.x >= 0.f ? o.x : 0.01f * o.x;
  o.y = o.y >= 0.f ? o.y : 0.01f * o.y;
  o.z = o.z >= 0.f ? o.z : 0.01f * o.z;
  o.w = o.w >= 0.f ? o.w : 0.01f * o.w;
  if (r) {
    float4 rv = *(const float4*)(r + (size_t)i * 512 + c);
    float4 rb = *(const float4*)(res_b + c);
    o.x += rv.x + rb.x; o.y += rv.y + rb.y; o.z += rv.z + rb.z; o.w += rv.w + rb.w;
  } else {
    float4 xv = *(const float4*)(xdst + (size_t)i * 512 + c);
    o.x += xv.x; o.y += xv.y; o.z += xv.z; o.w += xv.w;
  }
  *(float4*)(outp + (size_t)i * 512 + c) = o;
}

// ---------------------------------------------------------------------------
__global__ void feat_kernel(const float* __restrict__ x0, const float* __restrict__ x1,
                            const float* __restrict__ x2, const float* __restrict__ x3,
                            short* __restrict__ feat) {
  int i = blockIdx.x, t = threadIdx.x;
  int c = t * 8;
  int sel = c >> 9;
  const float* s = sel == 0 ? x0 : sel == 1 ? x1 : sel == 2 ? x2 : x3;
  int lc = c & 511;
  float4 a = *(const float4*)(s + (size_t)i * 512 + lc);
  float4 b = *(const float4*)(s + (size_t)i * 512 + lc + 4);
  short* d = feat + (size_t)i * 2048 + c;
  short4 o1; o1.x = f2bf(a.x); o1.y = f2bf(a.y); o1.z = f2bf(a.z); o1.w = f2bf(a.w);
  short4 o2; o2.x = f2bf(b.x); o2.y = f2bf(b.y); o2.z = f2bf(b.z); o2.w = f2bf(b.w);
  *(short4*)d = o1;
  *(short4*)(d + 4) = o2;
}

__global__ void tobf16_kernel(const float* __restrict__ in, short* __restrict__ outp, int n4) {
  int i = blockIdx.x * 256 + threadIdx.x;
  if (i < n4) {
    float4 v = ((const float4*)in)[i];
    short4 o; o.x = f2bf(v.x); o.y = f2bf(v.y); o.z = f2bf(v.z); o.w = f2bf(v.w);
    ((short4*)outp)[i] = o;
  }
}

// ---------------------------------------------------------------------------
__global__ void lsm_kernel(const float* __restrict__ z, float* __restrict__ outp) {
  __shared__ float redm[4], reds[4];
  int row = blockIdx.x, t = threadIdx.x;
  float v = z[(size_t)row * 256 + t];
  float m = v;
#pragma unroll
  for (int o = 32; o >= 1; o >>= 1) m = fmaxf(m, __shfl_down(m, o, 64));
  if ((t & 63) == 0) redm[t >> 6] = m;
  __syncthreads();
  m = fmaxf(fmaxf(redm[0], redm[1]), fmaxf(redm[2], redm[3]));
  float e = __expf(v - m);
  float s = e;
#pragma unroll
  for (int o = 32; o >= 1; o >>= 1) s += __shfl_down(s, o, 64);
  if ((t & 63) == 0) reds[t >> 6] = s;
  __syncthreads();
  s = reds[0] + reds[1] + reds[2] + reds[3];
  outp[(size_t)row * 256 + t] = v - m - __logf(s);
}

// ---------------------------------------------------------------------------
extern "C" void kernel_launch(void* const* d_in, const int* in_sizes, int n_in,
                              void* d_out, int out_size, void* d_ws, size_t ws_size,
                              hipStream_t stream) {
  const float* x0 = (const float*)d_in[0];
  const int* eis[3] = {(const int*)d_in[1], (const int*)d_in[2], (const int*)d_in[3]};
  const float* Wl[3] = {(const float*)d_in[4], (const float*)d_in[8], (const float*)d_in[12]};
  const float* Wr[3] = {(const float*)d_in[5], (const float*)d_in[9], (const float*)d_in[13]};
  const float* gg[3] = {(const float*)d_in[6], (const float*)d_in[10], (const float*)d_in[14]};
  const float* bb[3] = {(const float*)d_in[7], (const float*)d_in[11], (const float*)d_in[15]};
  const float* res_W = (const float*)d_in[16];
  const float* res_b = (const float*)d_in[17];
  const float* mlp_W1 = (const float*)d_in[18];
  const float* mlp_b1 = (const float*)d_in[19];
  const float* mlp_W2 = (const float*)d_in[20];
  const float* mlp_b2 = (const float*)d_in[21];
  float* out = (float*)d_out;

  const int Ns[4] = {60000, 30000, 15000, 8000};
  const int Es[3] = {300000, 150000, 80000};

  char* ws = (char*)d_ws;
  size_t off = 0;
  auto alloc = [&](size_t bytes) { size_t r = off; off += (bytes + 255) & ~(size_t)255; return r; };
  short* Bt[3];
  Bt[0] = (short*)(ws + alloc(512 * 1024 * 2));
  Bt[1] = (short*)(ws + alloc(512 * 1024 * 2));
  Bt[2] = (short*)(ws + alloc(512 * 1024 * 2));
  short* Rt = (short*)(ws + alloc(512 * 512 * 2));
  short* W1t = (short*)(ws + alloc(512 * 2048 * 2));
  short* W2t = (short*)(ws + alloc(256 * 512 * 2));
  int* deg = (int*)(ws + alloc(30001 * 4));
  int* offs = (int*)(ws + alloc(30001 * 4));
  int* cursor = (int*)(ws + alloc(30001 * 4));
  int* csr = (int*)(ws + alloc(300000 * 4));
  float* stats = (float*)(ws + alloc(2048 * 4));
  short* Abuf = (short*)(ws + alloc((size_t)30000 * 1024 * 2));
  size_t h_off = alloc((size_t)30000 * 512 * 4);
  float* h = (float*)(ws + h_off);
  size_t scr_off = alloc((size_t)30000 * 512 * 4);   // rbuf (L1) / z1,z1b,z2 (head)
  float* rbuf = (float*)(ws + scr_off);
  float* x1 = (float*)(ws + alloc((size_t)30000 * 512 * 4));
  float* x2 = (float*)(ws + alloc((size_t)15000 * 512 * 4));
  float* x3 = (float*)(ws + alloc((size_t)8000 * 512 * 4));
  // head overlays
  short* featb = (short*)(ws + h_off);               // 8000x2048 bf16 (h free by then)
  float* z1 = (float*)(ws + scr_off);                // 8000x512 f32
  short* z1b = (short*)(ws + scr_off + 16777216);    // 8000x512 bf16
  float* z2 = (float*)(ws + scr_off + 16777216 + 8388608); // 8000x256 f32

  // ---- weight prep (transpose + bf16) ----
  wconv_kernel<<<dim3(16, 16), 256, 0, stream>>>(Wl[0], Bt[0], 512, 512, 1024, 0);
  wconv_kernel<<<dim3(16, 16), 256, 0, stream>>>(Wr[0], Bt[0], 512, 512, 1024, 512);
  wconv_kernel<<<dim3(16, 16), 256, 0, stream>>>(Wl[1], Bt[1], 512, 512, 1024, 0);
  wconv_kernel<<<dim3(16, 16), 256, 0, stream>>>(Wr[1], Bt[1], 512, 512, 1024, 512);
  wconv_kernel<<<dim3(16, 16), 256, 0, stream>>>(Wl[2], Bt[2], 512, 512, 1024, 0);
  wconv_kernel<<<dim3(16, 16), 256, 0, stream>>>(Wr[2], Bt[2], 512, 512, 1024, 512);
  wconv_kernel<<<dim3(16, 16), 256, 0, stream>>>(res_W, Rt, 512, 512, 512, 0);
  wconv_kernel<<<dim3(64, 16), 256, 0, stream>>>(mlp_W1, W1t, 2048, 512, 2048, 0);
  wconv_kernel<<<dim3(16, 8), 256, 0, stream>>>(mlp_W2, W2t, 512, 256, 512, 0);

  const float* xin[3] = {x0, x1, x2};
  float* xout[3] = {x1, x2, x3};

  for (int l = 0; l < 3; ++l) {
    int n_dst = Ns[l + 1];
    int E = Es[l];
    // CSR build
    hipMemsetAsync(deg, 0, (size_t)(n_dst + 1) * 4, stream);
    hipMemsetAsync(cursor, 0, (size_t)(n_dst + 1) * 4, stream);
    deg_kernel<<<dim3((E + 255) / 256), 256, 0, stream>>>(eis[l], E, deg);
    scan_kernel<<<dim3(1), 256, 0, stream>>>(deg, offs, n_dst);
    fill_kernel<<<dim3((E + 255) / 256), 256, 0, stream>>>(eis[l], E, offs, cursor, csr);
    // gather aggregation + fused bf16 A build
    aggregate_kernel<<<dim3(n_dst), 256, 0, stream>>>(xin[l], csr, offs, Abuf, n_dst);
    int gm = (n_dst + 127) / 128;
    gemm_kernel<<<dim3(gm, 4), 256, 0, stream>>>(Abuf, 1024, Bt[l], 1024, h, 512,
                                                 n_dst, 512, 1024, nullptr);
    if (l == 0)
      gemm_kernel<<<dim3(gm, 4), 256, 0, stream>>>(Abuf + 512, 1024, Rt, 512, rbuf, 512,
                                                   n_dst, 512, 512, nullptr);
    hipMemsetAsync(stats, 0, 1024 * 4, stream);
    colstats_kernel<<<dim3((n_dst + 127) / 128), 256, 0, stream>>>(h, n_dst, stats);
    bnfin_kernel<<<dim3(2), 256, 0, stream>>>(stats, 1.0f / n_dst);
    apply_kernel<<<dim3(n_dst), 128, 0, stream>>>(h, stats, gg[l], bb[l],
                                                  l == 0 ? rbuf : nullptr, res_b,
                                                  xin[l], xout[l], n_dst);
  }

  // ---- head ----
  feat_kernel<<<dim3(8000), 256, 0, stream>>>(x0, x1, x2, x3, featb);
  gemm_kernel<<<dim3(63, 4), 256, 0, stream>>>(featb, 2048, W1t, 2048, z1, 512,
                                               8000, 512, 2048, mlp_b1);
  tobf16_kernel<<<dim3(4000), 256, 0, stream>>>(z1, z1b, 8000 * 512 / 4);
  gemm_kernel<<<dim3(63, 2), 256, 0, stream>>>(z1b, 512, W2t, 512, z2, 256,
                                               8000, 256, 512, mlp_b2);
  lsm_kernel<<<dim3(8000), 256, 0, stream>>>(z2, out);
}

// Round 3
// 932.017 us; speedup vs baseline: 4.6356x; 1.1062x over previous
//
#include <hip/hip_runtime.h>

typedef __attribute__((ext_vector_type(8))) short bf16x8;
typedef __attribute__((ext_vector_type(4))) float f32x4;

static __device__ __forceinline__ short f2bf(float f) {
  union { float f; unsigned u; } v; v.f = f;
  unsigned r = v.u + 0x7fffu + ((v.u >> 16) & 1u);
  return (short)(r >> 16);
}
static __device__ __forceinline__ float bf2f(short s) {
  union { unsigned u; float f; } v; v.u = ((unsigned)(unsigned short)s) << 16;
  return v.f;
}

#define GLOBAL_AS(p) ((const __attribute__((address_space(1))) void*)(p))
#define LDS_AS(p)    ((__attribute__((address_space(3))) void*)(p))

// ---------------------------------------------------------------------------
// Weight fp32 -> bf16 transposed: Wt[n*ldt + koff + k] = bf16(W[k*N + n])
__global__ void wconv_kernel(const float* __restrict__ W, short* __restrict__ Wt,
                             int K, int N, int ldt, int koff) {
  __shared__ float tile[32][33];
  int kb = blockIdx.x * 32, nb = blockIdx.y * 32;
  int tx = threadIdx.x & 31, ty = threadIdx.x >> 5;
#pragma unroll
  for (int j = 0; j < 4; ++j) {
    int k = kb + ty + 8 * j;
    tile[ty + 8 * j][tx] = W[(size_t)k * N + nb + tx];
  }
  __syncthreads();
#pragma unroll
  for (int j = 0; j < 4; ++j) {
    int n = nb + ty + 8 * j;
    Wt[(size_t)n * ldt + koff + kb + tx] = f2bf(tile[tx][ty + 8 * j]);
  }
}

// fp32 -> bf16 flat convert (8 elems/thread)
__global__ void conv_kernel(const float* __restrict__ in, short* __restrict__ outp, int n8) {
  int i = blockIdx.x * 256 + threadIdx.x;
  if (i < n8) {
    float4 a = ((const float4*)in)[i * 2];
    float4 b = ((const float4*)in)[i * 2 + 1];
    short4 o1; o1.x = f2bf(a.x); o1.y = f2bf(a.y); o1.z = f2bf(a.z); o1.w = f2bf(a.w);
    short4 o2; o2.x = f2bf(b.x); o2.y = f2bf(b.y); o2.z = f2bf(b.z); o2.w = f2bf(b.w);
    ((short4*)outp)[i * 2] = o1;
    ((short4*)outp)[i * 2 + 1] = o2;
  }
}

// ---------------------------------------------------------------------------
// CSR build
__global__ void deg_kernel(const int* __restrict__ ei, int E, int* __restrict__ deg) {
  int e = blockIdx.x * 256 + threadIdx.x;
  if (e < E) atomicAdd(&deg[ei[E + e]], 1);
}

__global__ void scan_kernel(const int* __restrict__ deg, int* __restrict__ offs, int n) {
  __shared__ int sums[257];
  int t = threadIdx.x;
  int per = (n + 255) / 256;
  int b = t * per, e = min(b + per, n);
  int s = 0;
  for (int i = b; i < e; ++i) s += deg[i];
  sums[t] = s;
  __syncthreads();
  if (t == 0) {
    int acc = 0;
    for (int i = 0; i < 256; ++i) { int v = sums[i]; sums[i] = acc; acc += v; }
    sums[256] = acc;
  }
  __syncthreads();
  int acc = sums[t];
  for (int i = b; i < e; ++i) { offs[i] = acc; acc += deg[i]; }
  if (t == 255) offs[n] = sums[256];
}

__global__ void fill_kernel(const int* __restrict__ ei, int E, const int* __restrict__ offs,
                            int* __restrict__ cursor, int* __restrict__ csr) {
  int e = blockIdx.x * 256 + threadIdx.x;
  if (e < E) {
    int d = ei[E + e];
    int p = atomicAdd(&cursor[d], 1);
    csr[offs[d] + p] = ei[e];
  }
}

// ---------------------------------------------------------------------------
// bf16 gather aggregation + fused A build.
// A[i] = [bf16(mean_{src} xb[src]) | xb[i]], row stride 1024. grid n_dst, block 128.
__global__ void aggregate_kernel(const short* __restrict__ xb, const int* __restrict__ csr,
                                 const int* __restrict__ offs, short* __restrict__ A,
                                 int n_dst) {
  int i = blockIdx.x;
  int t = threadIdx.x;          // 0..127, 4 cols each
  int s0 = offs[i], s1 = offs[i + 1];
  float a0 = 0.f, a1 = 0.f, a2 = 0.f, a3 = 0.f;
  const short* xp = xb + t * 4;
  int e = s0;
  for (; e + 3 < s1; e += 4) {
    short4 v0 = *(const short4*)(xp + (size_t)csr[e] * 512);
    short4 v1 = *(const short4*)(xp + (size_t)csr[e + 1] * 512);
    short4 v2 = *(const short4*)(xp + (size_t)csr[e + 2] * 512);
    short4 v3 = *(const short4*)(xp + (size_t)csr[e + 3] * 512);
    a0 += bf2f(v0.x) + bf2f(v1.x) + bf2f(v2.x) + bf2f(v3.x);
    a1 += bf2f(v0.y) + bf2f(v1.y) + bf2f(v2.y) + bf2f(v3.y);
    a2 += bf2f(v0.z) + bf2f(v1.z) + bf2f(v2.z) + bf2f(v3.z);
    a3 += bf2f(v0.w) + bf2f(v1.w) + bf2f(v2.w) + bf2f(v3.w);
  }
  for (; e < s1; ++e) {
    short4 v0 = *(const short4*)(xp + (size_t)csr[e] * 512);
    a0 += bf2f(v0.x); a1 += bf2f(v0.y); a2 += bf2f(v0.z); a3 += bf2f(v0.w);
  }
  float inv = (s1 > s0) ? 1.0f / (float)(s1 - s0) : 0.0f;
  short4 o;
  o.x = f2bf(a0 * inv); o.y = f2bf(a1 * inv); o.z = f2bf(a2 * inv); o.w = f2bf(a3 * inv);
  *(short4*)(A + (size_t)i * 1024 + t * 4) = o;
  *(short4*)(A + (size_t)i * 1024 + 512 + t * 4) = *(const short4*)(xp + (size_t)i * 512);
}

// ---------------------------------------------------------------------------
// bf16 MFMA GEMM: C(MxN) = A(MxK bf16, stride lda) @ Bt^T [+bias].
// Writes fp32 C or bf16 Cb (exactly one non-null).
__global__ __launch_bounds__(256, 2)
void gemm_kernel(const short* __restrict__ A, int lda,
                 const short* __restrict__ Bt, int ldb,
                 float* __restrict__ C, short* __restrict__ Cb, int ldc,
                 int M, int N, int K, const float* __restrict__ bias) {
  __shared__ short lds[8192];
  short* As = lds;
  short* Bs = lds + 4096;
  const int tid = threadIdx.x;
  const int wid = tid >> 6;
  const int lane = tid & 63;
  const int lm = lane & 15;
  const int quad = lane >> 4;
  const int wr = wid >> 1, wc = wid & 1;
  const int bm = blockIdx.x, bn = blockIdx.y;
  const int lrow = lane >> 2;
  const int lkb = (lane & 3) * 8;

  f32x4 acc[4][4];
#pragma unroll
  for (int i = 0; i < 4; ++i)
#pragma unroll
    for (int j = 0; j < 4; ++j) acc[i][j] = (f32x4)0.f;

  for (int k0 = 0; k0 < K; k0 += 32) {
#pragma unroll
    for (int j = 0; j < 2; ++j) {
      int ch = wid * 2 + j;
      int arow = bm * 128 + ch * 16 + lrow;
      arow = arow < M ? arow : M - 1;
      const short* ga = A + (size_t)arow * lda + k0 + lkb;
      __builtin_amdgcn_global_load_lds(GLOBAL_AS(ga), LDS_AS(As + ch * 512), 16, 0, 0);
      int brow = bn * 128 + ch * 16 + lrow;
      const short* gb = Bt + (size_t)brow * ldb + k0 + lkb;
      __builtin_amdgcn_global_load_lds(GLOBAL_AS(gb), LDS_AS(Bs + ch * 512), 16, 0, 0);
    }
    __syncthreads();
    bf16x8 af[4], bfr[4];
#pragma unroll
    for (int mi = 0; mi < 4; ++mi)
      af[mi] = *(const bf16x8*)(As + (wr * 64 + mi * 16 + lm) * 32 + quad * 8);
#pragma unroll
    for (int ni = 0; ni < 4; ++ni)
      bfr[ni] = *(const bf16x8*)(Bs + (wc * 64 + ni * 16 + lm) * 32 + quad * 8);
#pragma unroll
    for (int mi = 0; mi < 4; ++mi)
#pragma unroll
      for (int ni = 0; ni < 4; ++ni)
        acc[mi][ni] = __builtin_amdgcn_mfma_f32_16x16x32_bf16(af[mi], bfr[ni], acc[mi][ni], 0, 0, 0);
    __syncthreads();
  }

#pragma unroll
  for (int mi = 0; mi < 4; ++mi) {
#pragma unroll
    for (int ni = 0; ni < 4; ++ni) {
      int gcol = bn * 128 + wc * 64 + ni * 16 + lm;
      float bv = bias ? bias[gcol] : 0.f;
#pragma unroll
      for (int r2 = 0; r2 < 4; ++r2) {
        int grow = bm * 128 + wr * 64 + mi * 16 + quad * 4 + r2;
        if (grow < M) {
          float val = acc[mi][ni][r2] + bv;
          if (Cb) Cb[(size_t)grow * ldc + gcol] = f2bf(val);
          else    C[(size_t)grow * ldc + gcol] = val;
        }
      }
    }
  }
}

// ---------------------------------------------------------------------------
// Head GEMM-1: A staged directly from 4 bf16 x-buffers (concat along K).
__global__ __launch_bounds__(256, 2)
void gemm4_kernel(const short* __restrict__ p0, const short* __restrict__ p1,
                  const short* __restrict__ p2, const short* __restrict__ p3,
                  const short* __restrict__ Bt, int ldb,
                  short* __restrict__ Cb, int ldc,
                  int M, int N, const float* __restrict__ bias) {
  const int K = 2048;
  __shared__ short lds[8192];
  short* As = lds;
  short* Bs = lds + 4096;
  const int tid = threadIdx.x;
  const int wid = tid >> 6;
  const int lane = tid & 63;
  const int lm = lane & 15;
  const int quad = lane >> 4;
  const int wr = wid >> 1, wc = wid & 1;
  const int bm = blockIdx.x, bn = blockIdx.y;
  const int lrow = lane >> 2;
  const int lkb = (lane & 3) * 8;

  f32x4 acc[4][4];
#pragma unroll
  for (int i = 0; i < 4; ++i)
#pragma unroll
    for (int j = 0; j < 4; ++j) acc[i][j] = (f32x4)0.f;

  for (int k0 = 0; k0 < K; k0 += 32) {
    const short* Asrc = (k0 < 512) ? p0 : (k0 < 1024) ? p1 : (k0 < 1536) ? p2 : p3;
    int kloc = k0 & 511;
#pragma unroll
    for (int j = 0; j < 2; ++j) {
      int ch = wid * 2 + j;
      int arow = bm * 128 + ch * 16 + lrow;
      arow = arow < M ? arow : M - 1;
      const short* ga = Asrc + (size_t)arow * 512 + kloc + lkb;
      __builtin_amdgcn_global_load_lds(GLOBAL_AS(ga), LDS_AS(As + ch * 512), 16, 0, 0);
      int brow = bn * 128 + ch * 16 + lrow;
      const short* gb = Bt + (size_t)brow * ldb + k0 + lkb;
      __builtin_amdgcn_global_load_lds(GLOBAL_AS(gb), LDS_AS(Bs + ch * 512), 16, 0, 0);
    }
    __syncthreads();
    bf16x8 af[4], bfr[4];
#pragma unroll
    for (int mi = 0; mi < 4; ++mi)
      af[mi] = *(const bf16x8*)(As + (wr * 64 + mi * 16 + lm) * 32 + quad * 8);
#pragma unroll
    for (int ni = 0; ni < 4; ++ni)
      bfr[ni] = *(const bf16x8*)(Bs + (wc * 64 + ni * 16 + lm) * 32 + quad * 8);
#pragma unroll
    for (int mi = 0; mi < 4; ++mi)
#pragma unroll
      for (int ni = 0; ni < 4; ++ni)
        acc[mi][ni] = __builtin_amdgcn_mfma_f32_16x16x32_bf16(af[mi], bfr[ni], acc[mi][ni], 0, 0, 0);
    __syncthreads();
  }

#pragma unroll
  for (int mi = 0; mi < 4; ++mi) {
#pragma unroll
    for (int ni = 0; ni < 4; ++ni) {
      int gcol = bn * 128 + wc * 64 + ni * 16 + lm;
      float bv = bias[gcol];
#pragma unroll
      for (int r2 = 0; r2 < 4; ++r2) {
        int grow = bm * 128 + wr * 64 + mi * 16 + quad * 4 + r2;
        if (grow < M) Cb[(size_t)grow * ldc + gcol] = f2bf(acc[mi][ni][r2] + bv);
      }
    }
  }
}

// ---------------------------------------------------------------------------
__global__ void colstats_kernel(const float* __restrict__ h, int n, float* __restrict__ stats) {
  int c = threadIdx.x;
  int r0 = blockIdx.x * 128;
  int r1 = min(r0 + 128, n);
  float s1a = 0.f, s2a = 0.f, s1b = 0.f, s2b = 0.f;
  for (int r = r0; r < r1; ++r) {
    float a = h[(size_t)r * 512 + c];
    float b = h[(size_t)r * 512 + c + 256];
    s1a += a; s2a += a * a;
    s1b += b; s2b += b * b;
  }
  atomicAdd(&stats[c], s1a);
  atomicAdd(&stats[512 + c], s2a);
  atomicAdd(&stats[c + 256], s1b);
  atomicAdd(&stats[512 + c + 256], s2b);
}

__global__ void bnfin_kernel(float* __restrict__ stats, float inv_n) {
  int c = blockIdx.x * 256 + threadIdx.x;
  float mu = stats[c] * inv_n;
  float var = stats[512 + c] * inv_n - mu * mu;
  stats[1024 + c] = mu;
  stats[1536 + c] = rsqrtf(var + 1e-5f);
}

// ---------------------------------------------------------------------------
// x_out(bf16) = leaky(BN(h)) + (rbuf + res_b | bf16 xdst). grid n, block 128.
__global__ void apply_kernel(const float* __restrict__ h, const float* __restrict__ stats,
                             const float* __restrict__ g, const float* __restrict__ b,
                             const float* __restrict__ r, const float* __restrict__ res_b,
                             const short* __restrict__ xdst, short* __restrict__ outp, int n) {
  int i = blockIdx.x;
  int c = threadIdx.x * 4;
  float4 hv = *(const float4*)(h + (size_t)i * 512 + c);
  float4 mu = *(const float4*)(stats + 1024 + c);
  float4 rs = *(const float4*)(stats + 1536 + c);
  float4 gv = *(const float4*)(g + c);
  float4 bv = *(const float4*)(b + c);
  float4 o;
  o.x = (hv.x - mu.x) * rs.x * gv.x + bv.x;
  o.y = (hv.y - mu.y) * rs.y * gv.y + bv.y;
  o.z = (hv.z - mu.z) * rs.z * gv.z + bv.z;
  o.w = (hv.w - mu.w) * rs.w * gv.w + bv.w;
  o.x = o.x >= 0.f ? o.x : 0.01f * o.x;
  o.y = o.y >= 0.f ? o.y : 0.01f * o.y;
  o.z = o.z >= 0.f ? o.z : 0.01f * o.z;
  o.w = o.w >= 0.f ? o.w : 0.01f * o.w;
  if (r) {
    float4 rv = *(const float4*)(r + (size_t)i * 512 + c);
    float4 rb = *(const float4*)(res_b + c);
    o.x += rv.x + rb.x; o.y += rv.y + rb.y; o.z += rv.z + rb.z; o.w += rv.w + rb.w;
  } else {
    short4 xv = *(const short4*)(xdst + (size_t)i * 512 + c);
    o.x += bf2f(xv.x); o.y += bf2f(xv.y); o.z += bf2f(xv.z); o.w += bf2f(xv.w);
  }
  short4 ov;
  ov.x = f2bf(o.x); ov.y = f2bf(o.y); ov.z = f2bf(o.z); ov.w = f2bf(o.w);
  *(short4*)(outp + (size_t)i * 512 + c) = ov;
}

// ---------------------------------------------------------------------------
__global__ void lsm_kernel(const float* __restrict__ z, float* __restrict__ outp) {
  __shared__ float redm[4], reds[4];
  int row = blockIdx.x, t = threadIdx.x;
  float v = z[(size_t)row * 256 + t];
  float m = v;
#pragma unroll
  for (int o = 32; o >= 1; o >>= 1) m = fmaxf(m, __shfl_down(m, o, 64));
  if ((t & 63) == 0) redm[t >> 6] = m;
  __syncthreads();
  m = fmaxf(fmaxf(redm[0], redm[1]), fmaxf(redm[2], redm[3]));
  float e = __expf(v - m);
  float s = e;
#pragma unroll
  for (int o = 32; o >= 1; o >>= 1) s += __shfl_down(s, o, 64);
  if ((t & 63) == 0) reds[t >> 6] = s;
  __syncthreads();
  s = reds[0] + reds[1] + reds[2] + reds[3];
  outp[(size_t)row * 256 + t] = v - m - __logf(s);
}

// ---------------------------------------------------------------------------
extern "C" void kernel_launch(void* const* d_in, const int* in_sizes, int n_in,
                              void* d_out, int out_size, void* d_ws, size_t ws_size,
                              hipStream_t stream) {
  const float* x0 = (const float*)d_in[0];
  const int* eis[3] = {(const int*)d_in[1], (const int*)d_in[2], (const int*)d_in[3]};
  const float* Wl[3] = {(const float*)d_in[4], (const float*)d_in[8], (const float*)d_in[12]};
  const float* Wr[3] = {(const float*)d_in[5], (const float*)d_in[9], (const float*)d_in[13]};
  const float* gg[3] = {(const float*)d_in[6], (const float*)d_in[10], (const float*)d_in[14]};
  const float* bb[3] = {(const float*)d_in[7], (const float*)d_in[11], (const float*)d_in[15]};
  const float* res_W = (const float*)d_in[16];
  const float* res_b = (const float*)d_in[17];
  const float* mlp_W1 = (const float*)d_in[18];
  const float* mlp_b1 = (const float*)d_in[19];
  const float* mlp_W2 = (const float*)d_in[20];
  const float* mlp_b2 = (const float*)d_in[21];
  float* out = (float*)d_out;

  const int Ns[4] = {60000, 30000, 15000, 8000};
  const int Es[3] = {300000, 150000, 80000};

  char* ws = (char*)d_ws;
  size_t off = 0;
  auto alloc = [&](size_t bytes) { size_t r = off; off += (bytes + 255) & ~(size_t)255; return r; };
  short* Bt[3];
  Bt[0] = (short*)(ws + alloc(512 * 1024 * 2));
  Bt[1] = (short*)(ws + alloc(512 * 1024 * 2));
  Bt[2] = (short*)(ws + alloc(512 * 1024 * 2));
  short* Rt = (short*)(ws + alloc(512 * 512 * 2));
  short* W1t = (short*)(ws + alloc(512 * 2048 * 2));
  short* W2t = (short*)(ws + alloc(256 * 512 * 2));
  int* deg = (int*)(ws + alloc(30001 * 4));
  int* offs = (int*)(ws + alloc(30001 * 4));
  int* cursor = (int*)(ws + alloc(30001 * 4));
  int* csr = (int*)(ws + alloc(300000 * 4));
  float* stats = (float*)(ws + alloc(2048 * 4));
  short* xb0 = (short*)(ws + alloc((size_t)60000 * 512 * 2));
  short* x1b = (short*)(ws + alloc((size_t)30000 * 512 * 2));
  short* x2b = (short*)(ws + alloc((size_t)15000 * 512 * 2));
  short* x3b = (short*)(ws + alloc((size_t)8000 * 512 * 2));
  short* Abuf = (short*)(ws + alloc((size_t)30000 * 1024 * 2));
  float* h = (float*)(ws + alloc((size_t)30000 * 512 * 4));
  size_t scr_off = alloc((size_t)30000 * 512 * 4);   // rbuf (layer1) / z1b,z2 (head)
  float* rbuf = (float*)(ws + scr_off);
  short* z1b = (short*)(ws + scr_off);               // 8000x512 bf16
  float* z2 = (float*)(ws + scr_off + 8388608);      // 8000x256 f32

  // ---- weight prep ----
  wconv_kernel<<<dim3(16, 16), 256, 0, stream>>>(Wl[0], Bt[0], 512, 512, 1024, 0);
  wconv_kernel<<<dim3(16, 16), 256, 0, stream>>>(Wr[0], Bt[0], 512, 512, 1024, 512);
  wconv_kernel<<<dim3(16, 16), 256, 0, stream>>>(Wl[1], Bt[1], 512, 512, 1024, 0);
  wconv_kernel<<<dim3(16, 16), 256, 0, stream>>>(Wr[1], Bt[1], 512, 512, 1024, 512);
  wconv_kernel<<<dim3(16, 16), 256, 0, stream>>>(Wl[2], Bt[2], 512, 512, 1024, 0);
  wconv_kernel<<<dim3(16, 16), 256, 0, stream>>>(Wr[2], Bt[2], 512, 512, 1024, 512);
  wconv_kernel<<<dim3(16, 16), 256, 0, stream>>>(res_W, Rt, 512, 512, 512, 0);
  wconv_kernel<<<dim3(64, 16), 256, 0, stream>>>(mlp_W1, W1t, 2048, 512, 2048, 0);
  wconv_kernel<<<dim3(16, 8), 256, 0, stream>>>(mlp_W2, W2t, 512, 256, 512, 0);
  conv_kernel<<<dim3((60000 * 512 / 8 + 255) / 256), 256, 0, stream>>>(x0, xb0, 60000 * 512 / 8);

  const short* xin[3] = {xb0, x1b, x2b};
  short* xout[3] = {x1b, x2b, x3b};

  for (int l = 0; l < 3; ++l) {
    int n_dst = Ns[l + 1];
    int E = Es[l];
    hipMemsetAsync(deg, 0, (size_t)(n_dst + 1) * 4, stream);
    hipMemsetAsync(cursor, 0, (size_t)(n_dst + 1) * 4, stream);
    deg_kernel<<<dim3((E + 255) / 256), 256, 0, stream>>>(eis[l], E, deg);
    scan_kernel<<<dim3(1), 256, 0, stream>>>(deg, offs, n_dst);
    fill_kernel<<<dim3((E + 255) / 256), 256, 0, stream>>>(eis[l], E, offs, cursor, csr);
    aggregate_kernel<<<dim3(n_dst), 128, 0, stream>>>(xin[l], csr, offs, Abuf, n_dst);
    int gm = (n_dst + 127) / 128;
    gemm_kernel<<<dim3(gm, 4), 256, 0, stream>>>(Abuf, 1024, Bt[l], 1024, h, nullptr, 512,
                                                 n_dst, 512, 1024, nullptr);
    if (l == 0)
      gemm_kernel<<<dim3(gm, 4), 256, 0, stream>>>(Abuf + 512, 1024, Rt, 512, rbuf, nullptr, 512,
                                                   n_dst, 512, 512, nullptr);
    hipMemsetAsync(stats, 0, 1024 * 4, stream);
    colstats_kernel<<<dim3((n_dst + 127) / 128), 256, 0, stream>>>(h, n_dst, stats);
    bnfin_kernel<<<dim3(2), 256, 0, stream>>>(stats, 1.0f / n_dst);
    apply_kernel<<<dim3(n_dst), 128, 0, stream>>>(h, stats, gg[l], bb[l],
                                                  l == 0 ? rbuf : nullptr, res_b,
                                                  xin[l], xout[l], n_dst);
  }

  // ---- head ----
  gemm4_kernel<<<dim3(63, 4), 256, 0, stream>>>(xb0, x1b, x2b, x3b, W1t, 2048,
                                                z1b, 512, 8000, 512, mlp_b1);
  gemm_kernel<<<dim3(63, 2), 256, 0, stream>>>(z1b, 512, W2t, 512, z2, nullptr, 256,
                                               8000, 256, 512, mlp_b2);
  lsm_kernel<<<dim3(8000), 256, 0, stream>>>(z2, out);
}

// Round 4
// 815.255 us; speedup vs baseline: 5.2995x; 1.1432x over previous
//
#include <hip/hip_runtime.h>

typedef __attribute__((ext_vector_type(8))) short bf16x8;
typedef __attribute__((ext_vector_type(4))) float f32x4;

static __device__ __forceinline__ short f2bf(float f) {
  union { float f; unsigned u; } v; v.f = f;
  unsigned r = v.u + 0x7fffu + ((v.u >> 16) & 1u);
  return (short)(r >> 16);
}
static __device__ __forceinline__ float bf2f(short s) {
  union { unsigned u; float f; } v; v.u = ((unsigned)(unsigned short)s) << 16;
  return v.f;
}

#define GLOBAL_AS(p) ((const __attribute__((address_space(1))) void*)(p))
#define LDS_AS(p)    ((__attribute__((address_space(3))) void*)(p))

// ---------------------------------------------------------------------------
// Batched weight transpose+bf16 for seven 512x512 matrices (Wl/Wr x3 + res_W).
struct WDesc { const float* W; short* Wt; int ldt; int koff; };
struct WDesc7 { WDesc d[7]; };

__global__ void wconv7_kernel(WDesc7 ds) {
  __shared__ float tile[32][33];
  const WDesc dd = ds.d[blockIdx.z];
  int kb = blockIdx.x * 32, nb = blockIdx.y * 32;
  int tx = threadIdx.x & 31, ty = threadIdx.x >> 5;
#pragma unroll
  for (int j = 0; j < 4; ++j) {
    int k = kb + ty + 8 * j;
    tile[ty + 8 * j][tx] = dd.W[(size_t)k * 512 + nb + tx];
  }
  __syncthreads();
#pragma unroll
  for (int j = 0; j < 4; ++j) {
    int n = nb + ty + 8 * j;
    dd.Wt[(size_t)n * dd.ldt + dd.koff + kb + tx] = f2bf(tile[tx][ty + 8 * j]);
  }
}

// General single-matrix variant (mlp weights).
__global__ void wconv_kernel(const float* __restrict__ W, short* __restrict__ Wt,
                             int K, int N, int ldt, int koff) {
  __shared__ float tile[32][33];
  int kb = blockIdx.x * 32, nb = blockIdx.y * 32;
  int tx = threadIdx.x & 31, ty = threadIdx.x >> 5;
#pragma unroll
  for (int j = 0; j < 4; ++j) {
    int k = kb + ty + 8 * j;
    tile[ty + 8 * j][tx] = W[(size_t)k * N + nb + tx];
  }
  __syncthreads();
#pragma unroll
  for (int j = 0; j < 4; ++j) {
    int n = nb + ty + 8 * j;
    Wt[(size_t)n * ldt + koff + kb + tx] = f2bf(tile[tx][ty + 8 * j]);
  }
}

// fp32 -> bf16 flat convert (8 elems/thread)
__global__ void conv_kernel(const float* __restrict__ in, short* __restrict__ outp, int n8) {
  int i = blockIdx.x * 256 + threadIdx.x;
  if (i < n8) {
    float4 a = ((const float4*)in)[i * 2];
    float4 b = ((const float4*)in)[i * 2 + 1];
    short4 o1; o1.x = f2bf(a.x); o1.y = f2bf(a.y); o1.z = f2bf(a.z); o1.w = f2bf(a.w);
    short4 o2; o2.x = f2bf(b.x); o2.y = f2bf(b.y); o2.z = f2bf(b.z); o2.w = f2bf(b.w);
    ((short4*)outp)[i * 2] = o1;
    ((short4*)outp)[i * 2 + 1] = o2;
  }
}

// ---------------------------------------------------------------------------
// CSR build
__global__ void deg_kernel(const int* __restrict__ ei, int E, int* __restrict__ deg) {
  int e = blockIdx.x * 256 + threadIdx.x;
  if (e < E) atomicAdd(&deg[ei[E + e]], 1);
}

__global__ void scan_kernel(const int* __restrict__ deg, int* __restrict__ offs, int n) {
  __shared__ int sums[257];
  int t = threadIdx.x;
  int per = (n + 255) / 256;
  int b = t * per, e = min(b + per, n);
  int s = 0;
  for (int i = b; i < e; ++i) s += deg[i];
  sums[t] = s;
  __syncthreads();
  if (t == 0) {
    int acc = 0;
    for (int i = 0; i < 256; ++i) { int v = sums[i]; sums[i] = acc; acc += v; }
    sums[256] = acc;
  }
  __syncthreads();
  int acc = sums[t];
  for (int i = b; i < e; ++i) { offs[i] = acc; acc += deg[i]; }
  if (t == 255) offs[n] = sums[256];
}

__global__ void fill_kernel(const int* __restrict__ ei, int E, const int* __restrict__ offs,
                            int* __restrict__ cursor, int* __restrict__ csr) {
  int e = blockIdx.x * 256 + threadIdx.x;
  if (e < E) {
    int d = ei[E + e];
    int p = atomicAdd(&cursor[d], 1);
    csr[offs[d] + p] = ei[e];
  }
}

// ---------------------------------------------------------------------------
// bf16 gather aggregation + fused A build. grid n_dst, block 128.
__global__ void aggregate_kernel(const short* __restrict__ xb, const int* __restrict__ csr,
                                 const int* __restrict__ offs, short* __restrict__ A,
                                 int n_dst) {
  int i = blockIdx.x;
  int t = threadIdx.x;
  int s0 = offs[i], s1 = offs[i + 1];
  float a0 = 0.f, a1 = 0.f, a2 = 0.f, a3 = 0.f;
  const short* xp = xb + t * 4;
  int e = s0;
  for (; e + 3 < s1; e += 4) {
    short4 v0 = *(const short4*)(xp + (size_t)csr[e] * 512);
    short4 v1 = *(const short4*)(xp + (size_t)csr[e + 1] * 512);
    short4 v2 = *(const short4*)(xp + (size_t)csr[e + 2] * 512);
    short4 v3 = *(const short4*)(xp + (size_t)csr[e + 3] * 512);
    a0 += bf2f(v0.x) + bf2f(v1.x) + bf2f(v2.x) + bf2f(v3.x);
    a1 += bf2f(v0.y) + bf2f(v1.y) + bf2f(v2.y) + bf2f(v3.y);
    a2 += bf2f(v0.z) + bf2f(v1.z) + bf2f(v2.z) + bf2f(v3.z);
    a3 += bf2f(v0.w) + bf2f(v1.w) + bf2f(v2.w) + bf2f(v3.w);
  }
  for (; e < s1; ++e) {
    short4 v0 = *(const short4*)(xp + (size_t)csr[e] * 512);
    a0 += bf2f(v0.x); a1 += bf2f(v0.y); a2 += bf2f(v0.z); a3 += bf2f(v0.w);
  }
  float inv = (s1 > s0) ? 1.0f / (float)(s1 - s0) : 0.0f;
  short4 o;
  o.x = f2bf(a0 * inv); o.y = f2bf(a1 * inv); o.z = f2bf(a2 * inv); o.w = f2bf(a3 * inv);
  *(short4*)(A + (size_t)i * 1024 + t * 4) = o;
  *(short4*)(A + (size_t)i * 1024 + 512 + t * 4) = *(const short4*)(xp + (size_t)i * 512);
}

// ---------------------------------------------------------------------------
// bf16 MFMA GEMM. C fp32 or Cb bf16 (one non-null). Optional fused column
// stats: atomicAdd of sum(h) and sum(h^2) into stats[gcol], stats[512+gcol]
// (M-masked, computed from fp32 accumulators pre-rounding).
__global__ __launch_bounds__(256, 2)
void gemm_kernel(const short* __restrict__ A, int lda,
                 const short* __restrict__ Bt, int ldb,
                 float* __restrict__ C, short* __restrict__ Cb, int ldc,
                 int M, int N, int K, const float* __restrict__ bias,
                 float* __restrict__ stats) {
  __shared__ short lds[8192];
  short* As = lds;
  short* Bs = lds + 4096;
  const int tid = threadIdx.x;
  const int wid = tid >> 6;
  const int lane = tid & 63;
  const int lm = lane & 15;
  const int quad = lane >> 4;
  const int wr = wid >> 1, wc = wid & 1;
  const int bm = blockIdx.x, bn = blockIdx.y;
  const int lrow = lane >> 2;
  const int lkb = (lane & 3) * 8;

  f32x4 acc[4][4];
#pragma unroll
  for (int i = 0; i < 4; ++i)
#pragma unroll
    for (int j = 0; j < 4; ++j) acc[i][j] = (f32x4)0.f;

  for (int k0 = 0; k0 < K; k0 += 32) {
#pragma unroll
    for (int j = 0; j < 2; ++j) {
      int ch = wid * 2 + j;
      int arow = bm * 128 + ch * 16 + lrow;
      arow = arow < M ? arow : M - 1;
      const short* ga = A + (size_t)arow * lda + k0 + lkb;
      __builtin_amdgcn_global_load_lds(GLOBAL_AS(ga), LDS_AS(As + ch * 512), 16, 0, 0);
      int brow = bn * 128 + ch * 16 + lrow;
      const short* gb = Bt + (size_t)brow * ldb + k0 + lkb;
      __builtin_amdgcn_global_load_lds(GLOBAL_AS(gb), LDS_AS(Bs + ch * 512), 16, 0, 0);
    }
    __syncthreads();
    bf16x8 af[4], bfr[4];
#pragma unroll
    for (int mi = 0; mi < 4; ++mi)
      af[mi] = *(const bf16x8*)(As + (wr * 64 + mi * 16 + lm) * 32 + quad * 8);
#pragma unroll
    for (int ni = 0; ni < 4; ++ni)
      bfr[ni] = *(const bf16x8*)(Bs + (wc * 64 + ni * 16 + lm) * 32 + quad * 8);
#pragma unroll
    for (int mi = 0; mi < 4; ++mi)
#pragma unroll
      for (int ni = 0; ni < 4; ++ni)
        acc[mi][ni] = __builtin_amdgcn_mfma_f32_16x16x32_bf16(af[mi], bfr[ni], acc[mi][ni], 0, 0, 0);
    __syncthreads();
  }

#pragma unroll
  for (int mi = 0; mi < 4; ++mi) {
#pragma unroll
    for (int ni = 0; ni < 4; ++ni) {
      int gcol = bn * 128 + wc * 64 + ni * 16 + lm;
      float bv = bias ? bias[gcol] : 0.f;
#pragma unroll
      for (int r2 = 0; r2 < 4; ++r2) {
        int grow = bm * 128 + wr * 64 + mi * 16 + quad * 4 + r2;
        if (grow < M) {
          float val = acc[mi][ni][r2] + bv;
          if (Cb) Cb[(size_t)grow * ldc + gcol] = f2bf(val);
          else    C[(size_t)grow * ldc + gcol] = val;
        }
      }
    }
  }

  if (stats) {
    float* s1 = (float*)lds;          // 128 floats
    float* s2 = s1 + 128;
    if (tid < 128) { s1[tid] = 0.f; s2[tid] = 0.f; }
    __syncthreads();
#pragma unroll
    for (int ni = 0; ni < 4; ++ni) {
      int cloc = wc * 64 + ni * 16 + lm;
      float p1 = 0.f, p2 = 0.f;
#pragma unroll
      for (int mi = 0; mi < 4; ++mi)
#pragma unroll
        for (int r2 = 0; r2 < 4; ++r2) {
          int grow = bm * 128 + wr * 64 + mi * 16 + quad * 4 + r2;
          if (grow < M) {
            float v = acc[mi][ni][r2];
            p1 += v; p2 += v * v;
          }
        }
      atomicAdd(&s1[cloc], p1);
      atomicAdd(&s2[cloc], p2);
    }
    __syncthreads();
    if (tid < 128) {
      int gcol = bn * 128 + tid;
      atomicAdd(&stats[gcol], s1[tid]);
      atomicAdd(&stats[512 + gcol], s2[tid]);
    }
  }
}

// ---------------------------------------------------------------------------
// Head GEMM-1: A staged directly from 4 bf16 x-buffers (concat along K).
__global__ __launch_bounds__(256, 2)
void gemm4_kernel(const short* __restrict__ p0, const short* __restrict__ p1,
                  const short* __restrict__ p2, const short* __restrict__ p3,
                  const short* __restrict__ Bt, int ldb,
                  short* __restrict__ Cb, int ldc,
                  int M, int N, const float* __restrict__ bias) {
  const int K = 2048;
  __shared__ short lds[8192];
  short* As = lds;
  short* Bs = lds + 4096;
  const int tid = threadIdx.x;
  const int wid = tid >> 6;
  const int lane = tid & 63;
  const int lm = lane & 15;
  const int quad = lane >> 4;
  const int wr = wid >> 1, wc = wid & 1;
  const int bm = blockIdx.x, bn = blockIdx.y;
  const int lrow = lane >> 2;
  const int lkb = (lane & 3) * 8;

  f32x4 acc[4][4];
#pragma unroll
  for (int i = 0; i < 4; ++i)
#pragma unroll
    for (int j = 0; j < 4; ++j) acc[i][j] = (f32x4)0.f;

  for (int k0 = 0; k0 < K; k0 += 32) {
    const short* Asrc = (k0 < 512) ? p0 : (k0 < 1024) ? p1 : (k0 < 1536) ? p2 : p3;
    int kloc = k0 & 511;
#pragma unroll
    for (int j = 0; j < 2; ++j) {
      int ch = wid * 2 + j;
      int arow = bm * 128 + ch * 16 + lrow;
      arow = arow < M ? arow : M - 1;
      const short* ga = Asrc + (size_t)arow * 512 + kloc + lkb;
      __builtin_amdgcn_global_load_lds(GLOBAL_AS(ga), LDS_AS(As + ch * 512), 16, 0, 0);
      int brow = bn * 128 + ch * 16 + lrow;
      const short* gb = Bt + (size_t)brow * ldb + k0 + lkb;
      __builtin_amdgcn_global_load_lds(GLOBAL_AS(gb), LDS_AS(Bs + ch * 512), 16, 0, 0);
    }
    __syncthreads();
    bf16x8 af[4], bfr[4];
#pragma unroll
    for (int mi = 0; mi < 4; ++mi)
      af[mi] = *(const bf16x8*)(As + (wr * 64 + mi * 16 + lm) * 32 + quad * 8);
#pragma unroll
    for (int ni = 0; ni < 4; ++ni)
      bfr[ni] = *(const bf16x8*)(Bs + (wc * 64 + ni * 16 + lm) * 32 + quad * 8);
#pragma unroll
    for (int mi = 0; mi < 4; ++mi)
#pragma unroll
      for (int ni = 0; ni < 4; ++ni)
        acc[mi][ni] = __builtin_amdgcn_mfma_f32_16x16x32_bf16(af[mi], bfr[ni], acc[mi][ni], 0, 0, 0);
    __syncthreads();
  }

#pragma unroll
  for (int mi = 0; mi < 4; ++mi) {
#pragma unroll
    for (int ni = 0; ni < 4; ++ni) {
      int gcol = bn * 128 + wc * 64 + ni * 16 + lm;
      float bv = bias[gcol];
#pragma unroll
      for (int r2 = 0; r2 < 4; ++r2) {
        int grow = bm * 128 + wr * 64 + mi * 16 + quad * 4 + r2;
        if (grow < M) Cb[(size_t)grow * ldc + gcol] = f2bf(acc[mi][ni][r2] + bv);
      }
    }
  }
}

// ---------------------------------------------------------------------------
// x_out(bf16) = leaky(BN(h_bf16; stats)) + (rbuf_bf16 + res_b | xdst_bf16).
// mu/rstd derived inline from raw s1/s2. grid n, block 128.
__global__ void apply_kernel(const short* __restrict__ h, const float* __restrict__ stats,
                             const float* __restrict__ g, const float* __restrict__ b,
                             const short* __restrict__ r, const float* __restrict__ res_b,
                             const short* __restrict__ xdst, short* __restrict__ outp,
                             int n, float inv_n) {
  int i = blockIdx.x;
  int c = threadIdx.x * 4;
  short4 hb = *(const short4*)(h + (size_t)i * 512 + c);
  float4 s1 = *(const float4*)(stats + c);
  float4 s2 = *(const float4*)(stats + 512 + c);
  float4 gv = *(const float4*)(g + c);
  float4 bv = *(const float4*)(b + c);
  float mux = s1.x * inv_n, muy = s1.y * inv_n, muz = s1.z * inv_n, muw = s1.w * inv_n;
  float rsx = rsqrtf(s2.x * inv_n - mux * mux + 1e-5f);
  float rsy = rsqrtf(s2.y * inv_n - muy * muy + 1e-5f);
  float rsz = rsqrtf(s2.z * inv_n - muz * muz + 1e-5f);
  float rsw = rsqrtf(s2.w * inv_n - muw * muw + 1e-5f);
  float4 o;
  o.x = (bf2f(hb.x) - mux) * rsx * gv.x + bv.x;
  o.y = (bf2f(hb.y) - muy) * rsy * gv.y + bv.y;
  o.z = (bf2f(hb.z) - muz) * rsz * gv.z + bv.z;
  o.w = (bf2f(hb.w) - muw) * rsw * gv.w + bv.w;
  o.x = o.x >= 0.f ? o.x : 0.01f * o.x;
  o.y = o.y >= 0.f ? o.y : 0.01f * o.y;
  o.z = o.z >= 0.f ? o.z : 0.01f * o.z;
  o.w = o.w >= 0.f ? o.w : 0.01f * o.w;
  if (r) {
    short4 rv = *(const short4*)(r + (size_t)i * 512 + c);
    float4 rb = *(const float4*)(res_b + c);
    o.x += bf2f(rv.x) + rb.x; o.y += bf2f(rv.y) + rb.y;
    o.z += bf2f(rv.z) + rb.z; o.w += bf2f(rv.w) + rb.w;
  } else {
    short4 xv = *(const short4*)(xdst + (size_t)i * 512 + c);
    o.x += bf2f(xv.x); o.y += bf2f(xv.y); o.z += bf2f(xv.z); o.w += bf2f(xv.w);
  }
  short4 ov;
  ov.x = f2bf(o.x); ov.y = f2bf(o.y); ov.z = f2bf(o.z); ov.w = f2bf(o.w);
  *(short4*)(outp + (size_t)i * 512 + c) = ov;
}

// ---------------------------------------------------------------------------
__global__ void lsm_kernel(const float* __restrict__ z, float* __restrict__ outp) {
  __shared__ float redm[4], reds[4];
  int row = blockIdx.x, t = threadIdx.x;
  float v = z[(size_t)row * 256 + t];
  float m = v;
#pragma unroll
  for (int o = 32; o >= 1; o >>= 1) m = fmaxf(m, __shfl_down(m, o, 64));
  if ((t & 63) == 0) redm[t >> 6] = m;
  __syncthreads();
  m = fmaxf(fmaxf(redm[0], redm[1]), fmaxf(redm[2], redm[3]));
  float e = __expf(v - m);
  float s = e;
#pragma unroll
  for (int o = 32; o >= 1; o >>= 1) s += __shfl_down(s, o, 64);
  if ((t & 63) == 0) reds[t >> 6] = s;
  __syncthreads();
  s = reds[0] + reds[1] + reds[2] + reds[3];
  outp[(size_t)row * 256 + t] = v - m - __logf(s);
}

// ---------------------------------------------------------------------------
extern "C" void kernel_launch(void* const* d_in, const int* in_sizes, int n_in,
                              void* d_out, int out_size, void* d_ws, size_t ws_size,
                              hipStream_t stream) {
  const float* x0 = (const float*)d_in[0];
  const int* eis[3] = {(const int*)d_in[1], (const int*)d_in[2], (const int*)d_in[3]};
  const float* Wl[3] = {(const float*)d_in[4], (const float*)d_in[8], (const float*)d_in[12]};
  const float* Wr[3] = {(const float*)d_in[5], (const float*)d_in[9], (const float*)d_in[13]};
  const float* gg[3] = {(const float*)d_in[6], (const float*)d_in[10], (const float*)d_in[14]};
  const float* bb[3] = {(const float*)d_in[7], (const float*)d_in[11], (const float*)d_in[15]};
  const float* res_W = (const float*)d_in[16];
  const float* res_b = (const float*)d_in[17];
  const float* mlp_W1 = (const float*)d_in[18];
  const float* mlp_b1 = (const float*)d_in[19];
  const float* mlp_W2 = (const float*)d_in[20];
  const float* mlp_b2 = (const float*)d_in[21];
  float* out = (float*)d_out;

  const int Ns[4] = {60000, 30000, 15000, 8000};
  const int Es[3] = {300000, 150000, 80000};

  char* ws = (char*)d_ws;
  size_t off = 0;
  auto alloc = [&](size_t bytes) { size_t r = off; off += (bytes + 255) & ~(size_t)255; return r; };
  short* Bt[3];
  Bt[0] = (short*)(ws + alloc(512 * 1024 * 2));
  Bt[1] = (short*)(ws + alloc(512 * 1024 * 2));
  Bt[2] = (short*)(ws + alloc(512 * 1024 * 2));
  short* Rt = (short*)(ws + alloc(512 * 512 * 2));
  short* W1t = (short*)(ws + alloc(512 * 2048 * 2));
  short* W2t = (short*)(ws + alloc(256 * 512 * 2));
  int* deg = (int*)(ws + alloc(30001 * 4));
  int* offs = (int*)(ws + alloc(30001 * 4));
  int* cursor = (int*)(ws + alloc(30001 * 4));
  int* csr = (int*)(ws + alloc(300000 * 4));
  float* stats = (float*)(ws + alloc(1024 * 4));
  short* xb0 = (short*)(ws + alloc((size_t)60000 * 512 * 2));
  short* x1b = (short*)(ws + alloc((size_t)30000 * 512 * 2));
  short* x2b = (short*)(ws + alloc((size_t)15000 * 512 * 2));
  short* x3b = (short*)(ws + alloc((size_t)8000 * 512 * 2));
  short* Abuf = (short*)(ws + alloc((size_t)30000 * 1024 * 2));
  short* h = (short*)(ws + alloc((size_t)30000 * 512 * 2));
  size_t scr_off = alloc((size_t)30000 * 512 * 2);   // rbuf (layer1) / z1b (head)
  short* rbuf = (short*)(ws + scr_off);
  short* z1b = (short*)(ws + scr_off);               // 8000x512 bf16
  float* z2 = (float*)(ws + alloc((size_t)8000 * 256 * 4));

  // ---- weight prep ----
  WDesc7 wd;
  wd.d[0] = {Wl[0], Bt[0], 1024, 0};
  wd.d[1] = {Wr[0], Bt[0], 1024, 512};
  wd.d[2] = {Wl[1], Bt[1], 1024, 0};
  wd.d[3] = {Wr[1], Bt[1], 1024, 512};
  wd.d[4] = {Wl[2], Bt[2], 1024, 0};
  wd.d[5] = {Wr[2], Bt[2], 1024, 512};
  wd.d[6] = {res_W, Rt, 512, 0};
  wconv7_kernel<<<dim3(16, 16, 7), 256, 0, stream>>>(wd);
  wconv_kernel<<<dim3(64, 16), 256, 0, stream>>>(mlp_W1, W1t, 2048, 512, 2048, 0);
  wconv_kernel<<<dim3(16, 8), 256, 0, stream>>>(mlp_W2, W2t, 512, 256, 512, 0);
  conv_kernel<<<dim3((60000 * 512 / 8 + 255) / 256), 256, 0, stream>>>(x0, xb0, 60000 * 512 / 8);

  const short* xin[3] = {xb0, x1b, x2b};
  short* xout[3] = {x1b, x2b, x3b};

  for (int l = 0; l < 3; ++l) {
    int n_dst = Ns[l + 1];
    int E = Es[l];
    hipMemsetAsync(deg, 0, (size_t)(n_dst + 1) * 4, stream);
    hipMemsetAsync(cursor, 0, (size_t)(n_dst + 1) * 4, stream);
    hipMemsetAsync(stats, 0, 1024 * 4, stream);
    deg_kernel<<<dim3((E + 255) / 256), 256, 0, stream>>>(eis[l], E, deg);
    scan_kernel<<<dim3(1), 256, 0, stream>>>(deg, offs, n_dst);
    fill_kernel<<<dim3((E + 255) / 256), 256, 0, stream>>>(eis[l], E, offs, cursor, csr);
    aggregate_kernel<<<dim3(n_dst), 128, 0, stream>>>(xin[l], csr, offs, Abuf, n_dst);
    int gm = (n_dst + 127) / 128;
    gemm_kernel<<<dim3(gm, 4), 256, 0, stream>>>(Abuf, 1024, Bt[l], 1024, nullptr, h, 512,
                                                 n_dst, 512, 1024, nullptr, stats);
    if (l == 0)
      gemm_kernel<<<dim3(gm, 4), 256, 0, stream>>>(Abuf + 512, 1024, Rt, 512, nullptr, rbuf, 512,
                                                   n_dst, 512, 512, nullptr, nullptr);
    apply_kernel<<<dim3(n_dst), 128, 0, stream>>>(h, stats, gg[l], bb[l],
                                                  l == 0 ? rbuf : nullptr, res_b,
                                                  xin[l], xout[l], n_dst, 1.0f / n_dst);
  }

  // ---- head ----
  gemm4_kernel<<<dim3(63, 4), 256, 0, stream>>>(xb0, x1b, x2b, x3b, W1t, 2048,
                                                z1b, 512, 8000, 512, mlp_b1);
  gemm_kernel<<<dim3(63, 2), 256, 0, stream>>>(z1b, 512, W2t, 512, z2, nullptr, 256,
                                               8000, 256, 512, mlp_b2, nullptr);
  lsm_kernel<<<dim3(8000), 256, 0, stream>>>(z2, out);
}

// Round 5
// 738.542 us; speedup vs baseline: 5.8500x; 1.1039x over previous
//
#include <hip/hip_runtime.h>

typedef __attribute__((ext_vector_type(8))) short bf16x8;
typedef __attribute__((ext_vector_type(4))) float f32x4;

static __device__ __forceinline__ short f2bf(float f) {
  union { float f; unsigned u; } v; v.f = f;
  unsigned r = v.u + 0x7fffu + ((v.u >> 16) & 1u);
  return (short)(r >> 16);
}
static __device__ __forceinline__ float bf2f(short s) {
  union { unsigned u; float f; } v; v.u = ((unsigned)(unsigned short)s) << 16;
  return v.f;
}

#define GLOBAL_AS(p) ((const __attribute__((address_space(1))) void*)(p))
#define LDS_AS(p)    ((__attribute__((address_space(3))) void*)(p))

// ---------------------------------------------------------------------------
// Batched weight transpose+bf16: 12 descriptors (each a 512-row K-chunk).
struct WD { const float* W; short* Wt; int ldt; int koff; int Nn; };
struct WD12 { WD d[12]; };

__global__ void wconv12_kernel(WD12 ds) {
  __shared__ float tile[32][33];
  const WD dd = ds.d[blockIdx.z];
  int kb = blockIdx.x * 32, nb = blockIdx.y * 32;
  if (nb >= dd.Nn) return;
  int tx = threadIdx.x & 31, ty = threadIdx.x >> 5;
#pragma unroll
  for (int j = 0; j < 4; ++j) {
    int k = kb + ty + 8 * j;
    tile[ty + 8 * j][tx] = dd.W[(size_t)k * dd.Nn + nb + tx];
  }
  __syncthreads();
#pragma unroll
  for (int j = 0; j < 4; ++j) {
    int n = nb + ty + 8 * j;
    dd.Wt[(size_t)n * dd.ldt + dd.koff + kb + tx] = f2bf(tile[tx][ty + 8 * j]);
  }
}

// fp32 -> bf16 flat convert (8 elems/thread)
__global__ void conv_kernel(const float* __restrict__ in, short* __restrict__ outp, int n8) {
  int i = blockIdx.x * 256 + threadIdx.x;
  if (i < n8) {
    float4 a = ((const float4*)in)[i * 2];
    float4 b = ((const float4*)in)[i * 2 + 1];
    short4 o1; o1.x = f2bf(a.x); o1.y = f2bf(a.y); o1.z = f2bf(a.z); o1.w = f2bf(a.w);
    short4 o2; o2.x = f2bf(b.x); o2.y = f2bf(b.y); o2.z = f2bf(b.z); o2.w = f2bf(b.w);
    ((short4*)outp)[i * 2] = o1;
    ((short4*)outp)[i * 2 + 1] = o2;
  }
}

// ---------------------------------------------------------------------------
__global__ void zero3_kernel(int* a, int na, int* b, int nb2, float* c, int nc) {
  int i = blockIdx.x * 256 + threadIdx.x;
  if (i < na) a[i] = 0;
  if (i < nb2) b[i] = 0;
  if (i < nc) c[i] = 0.f;
}

// ---------------------------------------------------------------------------
// CSR build, all 3 layers.
struct L3s { const int* ei[3]; int E[3]; int dbase[3]; int ebase[3]; };

__global__ void deg_all_kernel(L3s L, int* __restrict__ deg) {
  int g = blockIdx.x * 256 + threadIdx.x;
  int l = 0, e = g;
  while (l < 3 && e >= L.E[l]) { e -= L.E[l]; ++l; }
  if (l >= 3) return;
  int d = L.ei[l][L.E[l] + e];
  atomicAdd(&deg[L.dbase[l] + d], 1);
}

// one block (256 thr) per layer; layer size passed in Ln.E[l]
__global__ void scan_all_kernel(L3s Ln, const int* __restrict__ deg, int* __restrict__ offs) {
  __shared__ int sums[257];
  int l = blockIdx.x;
  int n = Ln.E[l];
  const int* dg = deg + Ln.dbase[l];
  int* of = offs + Ln.dbase[l];
  int t = threadIdx.x;
  int per = (n + 255) / 256;
  int b = t * per, e = min(b + per, n);
  int s = 0;
  for (int i = b; i < e; ++i) s += dg[i];
  sums[t] = s;
  __syncthreads();
  if (t == 0) {
    int acc = 0;
    for (int i = 0; i < 256; ++i) { int v = sums[i]; sums[i] = acc; acc += v; }
    sums[256] = acc;
  }
  __syncthreads();
  int acc = sums[t];
  for (int i = b; i < e; ++i) { of[i] = acc; acc += dg[i]; }
  if (t == 255) of[n] = sums[256];
}

__global__ void fill_all_kernel(L3s L, const int* __restrict__ offs,
                                int* __restrict__ cursor, int* __restrict__ csr) {
  int g = blockIdx.x * 256 + threadIdx.x;
  int l = 0, e = g;
  while (l < 3 && e >= L.E[l]) { e -= L.E[l]; ++l; }
  if (l >= 3) return;
  int d = L.ei[l][L.E[l] + e];
  int p = atomicAdd(&cursor[L.dbase[l] + d], 1);
  csr[L.ebase[l] + offs[L.dbase[l] + d] + p] = L.ei[l][e];
}

// ---------------------------------------------------------------------------
// Gather aggregation + fused A build, wave-per-node (4 nodes / 256-thr block).
__global__ void aggregate_kernel(const short* __restrict__ xb, const int* __restrict__ csr,
                                 const int* __restrict__ offs, short* __restrict__ A,
                                 int n_dst) {
  int node = blockIdx.x * 4 + (threadIdx.x >> 6);
  if (node >= n_dst) return;
  int lane = threadIdx.x & 63;
  const short* xp = xb + lane * 8;
  int s0 = offs[node], s1 = offs[node + 1];
  float a[8];
#pragma unroll
  for (int j = 0; j < 8; ++j) a[j] = 0.f;
  int e = s0;
  for (; e + 1 < s1; e += 2) {
    bf16x8 v0 = *(const bf16x8*)(xp + (size_t)csr[e] * 512);
    bf16x8 v1 = *(const bf16x8*)(xp + (size_t)csr[e + 1] * 512);
#pragma unroll
    for (int j = 0; j < 8; ++j) a[j] += bf2f(v0[j]) + bf2f(v1[j]);
  }
  if (e < s1) {
    bf16x8 v0 = *(const bf16x8*)(xp + (size_t)csr[e] * 512);
#pragma unroll
    for (int j = 0; j < 8; ++j) a[j] += bf2f(v0[j]);
  }
  float inv = (s1 > s0) ? 1.0f / (float)(s1 - s0) : 0.0f;
  bf16x8 o;
#pragma unroll
  for (int j = 0; j < 8; ++j) o[j] = f2bf(a[j] * inv);
  *(bf16x8*)(A + (size_t)node * 1024 + lane * 8) = o;
  *(bf16x8*)(A + (size_t)node * 1024 + 512 + lane * 8) =
      *(const bf16x8*)(xp + (size_t)node * 512);
}

// ---------------------------------------------------------------------------
// bf16 MFMA GEMM. C fp32 or Cb bf16 (one non-null). Optional fused column stats.
__global__ __launch_bounds__(256, 2)
void gemm_kernel(const short* __restrict__ A, int lda,
                 const short* __restrict__ Bt, int ldb,
                 float* __restrict__ C, short* __restrict__ Cb, int ldc,
                 int M, int N, int K, const float* __restrict__ bias,
                 float* __restrict__ stats) {
  __shared__ short lds[8192];
  short* As = lds;
  short* Bs = lds + 4096;
  const int tid = threadIdx.x;
  const int wid = tid >> 6;
  const int lane = tid & 63;
  const int lm = lane & 15;
  const int quad = lane >> 4;
  const int wr = wid >> 1, wc = wid & 1;
  const int bm = blockIdx.x, bn = blockIdx.y;
  const int lrow = lane >> 2;
  const int lkb = (lane & 3) * 8;

  f32x4 acc[4][4];
#pragma unroll
  for (int i = 0; i < 4; ++i)
#pragma unroll
    for (int j = 0; j < 4; ++j) acc[i][j] = (f32x4)0.f;

  for (int k0 = 0; k0 < K; k0 += 32) {
#pragma unroll
    for (int j = 0; j < 2; ++j) {
      int ch = wid * 2 + j;
      int arow = bm * 128 + ch * 16 + lrow;
      arow = arow < M ? arow : M - 1;
      const short* ga = A + (size_t)arow * lda + k0 + lkb;
      __builtin_amdgcn_global_load_lds(GLOBAL_AS(ga), LDS_AS(As + ch * 512), 16, 0, 0);
      int brow = bn * 128 + ch * 16 + lrow;
      const short* gb = Bt + (size_t)brow * ldb + k0 + lkb;
      __builtin_amdgcn_global_load_lds(GLOBAL_AS(gb), LDS_AS(Bs + ch * 512), 16, 0, 0);
    }
    __syncthreads();
    bf16x8 af[4], bfr[4];
#pragma unroll
    for (int mi = 0; mi < 4; ++mi)
      af[mi] = *(const bf16x8*)(As + (wr * 64 + mi * 16 + lm) * 32 + quad * 8);
#pragma unroll
    for (int ni = 0; ni < 4; ++ni)
      bfr[ni] = *(const bf16x8*)(Bs + (wc * 64 + ni * 16 + lm) * 32 + quad * 8);
#pragma unroll
    for (int mi = 0; mi < 4; ++mi)
#pragma unroll
      for (int ni = 0; ni < 4; ++ni)
        acc[mi][ni] = __builtin_amdgcn_mfma_f32_16x16x32_bf16(af[mi], bfr[ni], acc[mi][ni], 0, 0, 0);
    __syncthreads();
  }

#pragma unroll
  for (int mi = 0; mi < 4; ++mi) {
#pragma unroll
    for (int ni = 0; ni < 4; ++ni) {
      int gcol = bn * 128 + wc * 64 + ni * 16 + lm;
      float bv = bias ? bias[gcol] : 0.f;
#pragma unroll
      for (int r2 = 0; r2 < 4; ++r2) {
        int grow = bm * 128 + wr * 64 + mi * 16 + quad * 4 + r2;
        if (grow < M) {
          float val = acc[mi][ni][r2] + bv;
          if (Cb) Cb[(size_t)grow * ldc + gcol] = f2bf(val);
          else    C[(size_t)grow * ldc + gcol] = val;
        }
      }
    }
  }

  if (stats) {
    float* s1 = (float*)lds;
    float* s2 = s1 + 128;
    if (tid < 128) { s1[tid] = 0.f; s2[tid] = 0.f; }
    __syncthreads();
#pragma unroll
    for (int ni = 0; ni < 4; ++ni) {
      int cloc = wc * 64 + ni * 16 + lm;
      float p1 = 0.f, p2 = 0.f;
#pragma unroll
      for (int mi = 0; mi < 4; ++mi)
#pragma unroll
        for (int r2 = 0; r2 < 4; ++r2) {
          int grow = bm * 128 + wr * 64 + mi * 16 + quad * 4 + r2;
          if (grow < M) {
            float v = acc[mi][ni][r2];
            p1 += v; p2 += v * v;
          }
        }
      atomicAdd(&s1[cloc], p1);
      atomicAdd(&s2[cloc], p2);
    }
    __syncthreads();
    if (tid < 128) {
      int gcol = bn * 128 + tid;
      atomicAdd(&stats[gcol], s1[tid]);
      atomicAdd(&stats[512 + gcol], s2[tid]);
    }
  }
}

// ---------------------------------------------------------------------------
// Head GEMM-1: A staged directly from 4 bf16 x-buffers (concat along K).
__global__ __launch_bounds__(256, 2)
void gemm4_kernel(const short* __restrict__ p0, const short* __restrict__ p1,
                  const short* __restrict__ p2, const short* __restrict__ p3,
                  const short* __restrict__ Bt, int ldb,
                  short* __restrict__ Cb, int ldc,
                  int M, int N, const float* __restrict__ bias) {
  const int K = 2048;
  __shared__ short lds[8192];
  short* As = lds;
  short* Bs = lds + 4096;
  const int tid = threadIdx.x;
  const int wid = tid >> 6;
  const int lane = tid & 63;
  const int lm = lane & 15;
  const int quad = lane >> 4;
  const int wr = wid >> 1, wc = wid & 1;
  const int bm = blockIdx.x, bn = blockIdx.y;
  const int lrow = lane >> 2;
  const int lkb = (lane & 3) * 8;

  f32x4 acc[4][4];
#pragma unroll
  for (int i = 0; i < 4; ++i)
#pragma unroll
    for (int j = 0; j < 4; ++j) acc[i][j] = (f32x4)0.f;

  for (int k0 = 0; k0 < K; k0 += 32) {
    const short* Asrc = (k0 < 512) ? p0 : (k0 < 1024) ? p1 : (k0 < 1536) ? p2 : p3;
    int kloc = k0 & 511;
#pragma unroll
    for (int j = 0; j < 2; ++j) {
      int ch = wid * 2 + j;
      int arow = bm * 128 + ch * 16 + lrow;
      arow = arow < M ? arow : M - 1;
      const short* ga = Asrc + (size_t)arow * 512 + kloc + lkb;
      __builtin_amdgcn_global_load_lds(GLOBAL_AS(ga), LDS_AS(As + ch * 512), 16, 0, 0);
      int brow = bn * 128 + ch * 16 + lrow;
      const short* gb = Bt + (size_t)brow * ldb + k0 + lkb;
      __builtin_amdgcn_global_load_lds(GLOBAL_AS(gb), LDS_AS(Bs + ch * 512), 16, 0, 0);
    }
    __syncthreads();
    bf16x8 af[4], bfr[4];
#pragma unroll
    for (int mi = 0; mi < 4; ++mi)
      af[mi] = *(const bf16x8*)(As + (wr * 64 + mi * 16 + lm) * 32 + quad * 8);
#pragma unroll
    for (int ni = 0; ni < 4; ++ni)
      bfr[ni] = *(const bf16x8*)(Bs + (wc * 64 + ni * 16 + lm) * 32 + quad * 8);
#pragma unroll
    for (int mi = 0; mi < 4; ++mi)
#pragma unroll
      for (int ni = 0; ni < 4; ++ni)
        acc[mi][ni] = __builtin_amdgcn_mfma_f32_16x16x32_bf16(af[mi], bfr[ni], acc[mi][ni], 0, 0, 0);
    __syncthreads();
  }

#pragma unroll
  for (int mi = 0; mi < 4; ++mi) {
#pragma unroll
    for (int ni = 0; ni < 4; ++ni) {
      int gcol = bn * 128 + wc * 64 + ni * 16 + lm;
      float bv = bias[gcol];
#pragma unroll
      for (int r2 = 0; r2 < 4; ++r2) {
        int grow = bm * 128 + wr * 64 + mi * 16 + quad * 4 + r2;
        if (grow < M) Cb[(size_t)grow * ldc + gcol] = f2bf(acc[mi][ni][r2] + bv);
      }
    }
  }
}

// ---------------------------------------------------------------------------
// x_out(bf16) = leaky(BN(h_bf16; stats)) + (rbuf_bf16 + res_b | xdst_bf16).
__global__ void apply_kernel(const short* __restrict__ h, const float* __restrict__ stats,
                             const float* __restrict__ g, const float* __restrict__ b,
                             const short* __restrict__ r, const float* __restrict__ res_b,
                             const short* __restrict__ xdst, short* __restrict__ outp,
                             int n, float inv_n) {
  int i = blockIdx.x;
  int c = threadIdx.x * 4;
  short4 hb = *(const short4*)(h + (size_t)i * 512 + c);
  float4 s1 = *(const float4*)(stats + c);
  float4 s2 = *(const float4*)(stats + 512 + c);
  float4 gv = *(const float4*)(g + c);
  float4 bv = *(const float4*)(b + c);
  float mux = s1.x * inv_n, muy = s1.y * inv_n, muz = s1.z * inv_n, muw = s1.w * inv_n;
  float rsx = rsqrtf(s2.x * inv_n - mux * mux + 1e-5f);
  float rsy = rsqrtf(s2.y * inv_n - muy * muy + 1e-5f);
  float rsz = rsqrtf(s2.z * inv_n - muz * muz + 1e-5f);
  float rsw = rsqrtf(s2.w * inv_n - muw * muw + 1e-5f);
  float4 o;
  o.x = (bf2f(hb.x) - mux) * rsx * gv.x + bv.x;
  o.y = (bf2f(hb.y) - muy) * rsy * gv.y + bv.y;
  o.z = (bf2f(hb.z) - muz) * rsz * gv.z + bv.z;
  o.w = (bf2f(hb.w) - muw) * rsw * gv.w + bv.w;
  o.x = o.x >= 0.f ? o.x : 0.01f * o.x;
  o.y = o.y >= 0.f ? o.y : 0.01f * o.y;
  o.z = o.z >= 0.f ? o.z : 0.01f * o.z;
  o.w = o.w >= 0.f ? o.w : 0.01f * o.w;
  if (r) {
    short4 rv = *(const short4*)(r + (size_t)i * 512 + c);
    float4 rb = *(const float4*)(res_b + c);
    o.x += bf2f(rv.x) + rb.x; o.y += bf2f(rv.y) + rb.y;
    o.z += bf2f(rv.z) + rb.z; o.w += bf2f(rv.w) + rb.w;
  } else {
    short4 xv = *(const short4*)(xdst + (size_t)i * 512 + c);
    o.x += bf2f(xv.x); o.y += bf2f(xv.y); o.z += bf2f(xv.z); o.w += bf2f(xv.w);
  }
  short4 ov;
  ov.x = f2bf(o.x); ov.y = f2bf(o.y); ov.z = f2bf(o.z); ov.w = f2bf(o.w);
  *(short4*)(outp + (size_t)i * 512 + c) = ov;
}

// ---------------------------------------------------------------------------
__global__ void lsm_kernel(const float* __restrict__ z, float* __restrict__ outp) {
  __shared__ float redm[4], reds[4];
  int row = blockIdx.x, t = threadIdx.x;
  float v = z[(size_t)row * 256 + t];
  float m = v;
#pragma unroll
  for (int o = 32; o >= 1; o >>= 1) m = fmaxf(m, __shfl_down(m, o, 64));
  if ((t & 63) == 0) redm[t >> 6] = m;
  __syncthreads();
  m = fmaxf(fmaxf(redm[0], redm[1]), fmaxf(redm[2], redm[3]));
  float e = __expf(v - m);
  float s = e;
#pragma unroll
  for (int o = 32; o >= 1; o >>= 1) s += __shfl_down(s, o, 64);
  if ((t & 63) == 0) reds[t >> 6] = s;
  __syncthreads();
  s = reds[0] + reds[1] + reds[2] + reds[3];
  outp[(size_t)row * 256 + t] = v - m - __logf(s);
}

// ---------------------------------------------------------------------------
extern "C" void kernel_launch(void* const* d_in, const int* in_sizes, int n_in,
                              void* d_out, int out_size, void* d_ws, size_t ws_size,
                              hipStream_t stream) {
  const float* x0 = (const float*)d_in[0];
  const int* eis[3] = {(const int*)d_in[1], (const int*)d_in[2], (const int*)d_in[3]};
  const float* Wl[3] = {(const float*)d_in[4], (const float*)d_in[8], (const float*)d_in[12]};
  const float* Wr[3] = {(const float*)d_in[5], (const float*)d_in[9], (const float*)d_in[13]};
  const float* gg[3] = {(const float*)d_in[6], (const float*)d_in[10], (const float*)d_in[14]};
  const float* bb[3] = {(const float*)d_in[7], (const float*)d_in[11], (const float*)d_in[15]};
  const float* res_W = (const float*)d_in[16];
  const float* res_b = (const float*)d_in[17];
  const float* mlp_W1 = (const float*)d_in[18];
  const float* mlp_b1 = (const float*)d_in[19];
  const float* mlp_W2 = (const float*)d_in[20];
  const float* mlp_b2 = (const float*)d_in[21];
  float* out = (float*)d_out;

  const int Ns[4] = {60000, 30000, 15000, 8000};
  int Es[3];
  for (int l = 0; l < 3; ++l) Es[l] = in_sizes[1 + l] / 2;
  int Etot = Es[0] + Es[1] + Es[2];

  char* ws = (char*)d_ws;
  size_t off = 0;
  auto alloc = [&](size_t bytes) { size_t r = off; off += (bytes + 255) & ~(size_t)255; return r; };
  short* Bt[3];
  Bt[0] = (short*)(ws + alloc(512 * 1024 * 2));
  Bt[1] = (short*)(ws + alloc(512 * 1024 * 2));
  Bt[2] = (short*)(ws + alloc(512 * 1024 * 2));
  short* Rt = (short*)(ws + alloc(512 * 512 * 2));
  short* W1t = (short*)(ws + alloc(512 * 2048 * 2));
  short* W2t = (short*)(ws + alloc(256 * 512 * 2));
  const int dbase[3] = {0, 30001, 45002};
  const int ndeg = 53003;
  int ebase[3] = {0, Es[0], Es[0] + Es[1]};
  int* deg3 = (int*)(ws + alloc((size_t)ndeg * 4));
  int* offs3 = (int*)(ws + alloc((size_t)ndeg * 4));
  int* cursor3 = (int*)(ws + alloc((size_t)ndeg * 4));
  int* csr3 = (int*)(ws + alloc((size_t)Etot * 4));
  float* stats3 = (float*)(ws + alloc(3 * 1024 * 4));
  short* xb0 = (short*)(ws + alloc((size_t)60000 * 512 * 2));
  short* x1b = (short*)(ws + alloc((size_t)30000 * 512 * 2));
  short* x2b = (short*)(ws + alloc((size_t)15000 * 512 * 2));
  short* x3b = (short*)(ws + alloc((size_t)8000 * 512 * 2));
  short* Abuf = (short*)(ws + alloc((size_t)30000 * 1024 * 2));
  short* h = (short*)(ws + alloc((size_t)30000 * 512 * 2));
  size_t scr_off = alloc((size_t)30000 * 512 * 2);
  short* rbuf = (short*)(ws + scr_off);
  short* z1b = (short*)(ws + scr_off);
  float* z2 = (float*)(ws + alloc((size_t)8000 * 256 * 4));

  // ---- weight prep: one batched dispatch + x0 conversion ----
  WD12 wd;
  wd.d[0] = {Wl[0], Bt[0], 1024, 0, 512};
  wd.d[1] = {Wr[0], Bt[0], 1024, 512, 512};
  wd.d[2] = {Wl[1], Bt[1], 1024, 0, 512};
  wd.d[3] = {Wr[1], Bt[1], 1024, 512, 512};
  wd.d[4] = {Wl[2], Bt[2], 1024, 0, 512};
  wd.d[5] = {Wr[2], Bt[2], 1024, 512, 512};
  wd.d[6] = {res_W, Rt, 512, 0, 512};
  wd.d[7] = {mlp_W1 + 0 * 512 * 512, W1t, 2048, 0, 512};
  wd.d[8] = {mlp_W1 + 1 * 512 * 512, W1t, 2048, 512, 512};
  wd.d[9] = {mlp_W1 + 2 * 512 * 512, W1t, 2048, 1024, 512};
  wd.d[10] = {mlp_W1 + 3 * 512 * 512, W1t, 2048, 1536, 512};
  wd.d[11] = {mlp_W2, W2t, 512, 0, 256};
  wconv12_kernel<<<dim3(16, 16, 12), 256, 0, stream>>>(wd);
  conv_kernel<<<dim3((60000 * 512 / 8 + 255) / 256), 256, 0, stream>>>(x0, xb0, 60000 * 512 / 8);

  // ---- CSR build: 4 dispatches for all 3 layers ----
  L3s L;
  for (int l = 0; l < 3; ++l) {
    L.ei[l] = eis[l]; L.E[l] = Es[l]; L.dbase[l] = dbase[l]; L.ebase[l] = ebase[l];
  }
  zero3_kernel<<<dim3((ndeg + 255) / 256), 256, 0, stream>>>(deg3, ndeg, cursor3, ndeg,
                                                             stats3, 3 * 1024);
  deg_all_kernel<<<dim3((Etot + 255) / 256), 256, 0, stream>>>(L, deg3);
  L3s Ln = L;
  Ln.E[0] = Ns[1]; Ln.E[1] = Ns[2]; Ln.E[2] = Ns[3];
  scan_all_kernel<<<dim3(3), 256, 0, stream>>>(Ln, deg3, offs3);
  fill_all_kernel<<<dim3((Etot + 255) / 256), 256, 0, stream>>>(L, offs3, cursor3, csr3);

  const short* xin[3] = {xb0, x1b, x2b};
  short* xout[3] = {x1b, x2b, x3b};

  for (int l = 0; l < 3; ++l) {
    int n_dst = Ns[l + 1];
    float* stats = stats3 + l * 1024;
    aggregate_kernel<<<dim3((n_dst + 3) / 4), 256, 0, stream>>>(
        xin[l], csr3 + ebase[l], offs3 + dbase[l], Abuf, n_dst);
    int gm = (n_dst + 127) / 128;
    gemm_kernel<<<dim3(gm, 4), 256, 0, stream>>>(Abuf, 1024, Bt[l], 1024, nullptr, h, 512,
                                                 n_dst, 512, 1024, nullptr, stats);
    if (l == 0)
      gemm_kernel<<<dim3(gm, 4), 256, 0, stream>>>(Abuf + 512, 1024, Rt, 512, nullptr, rbuf, 512,
                                                   n_dst, 512, 512, nullptr, nullptr);
    apply_kernel<<<dim3(n_dst), 128, 0, stream>>>(h, stats, gg[l], bb[l],
                                                  l == 0 ? rbuf : nullptr, res_b,
                                                  xin[l], xout[l], n_dst, 1.0f / n_dst);
  }

  // ---- head ----
  gemm4_kernel<<<dim3(63, 4), 256, 0, stream>>>(xb0, x1b, x2b, x3b, W1t, 2048,
                                                z1b, 512, 8000, 512, mlp_b1);
  gemm_kernel<<<dim3(63, 2), 256, 0, stream>>>(z1b, 512, W2t, 512, z2, nullptr, 256,
                                               8000, 256, 512, mlp_b2, nullptr);
  lsm_kernel<<<dim3(8000), 256, 0, stream>>>(z2, out);
}

// Round 6
// 690.548 us; speedup vs baseline: 6.2565x; 1.0695x over previous
//
#include <hip/hip_runtime.h>

typedef __attribute__((ext_vector_type(8))) short bf16x8;
typedef __attribute__((ext_vector_type(4))) float f32x4;

static __device__ __forceinline__ short f2bf(float f) {
  union { float f; unsigned u; } v; v.f = f;
  unsigned r = v.u + 0x7fffu + ((v.u >> 16) & 1u);
  return (short)(r >> 16);
}
static __device__ __forceinline__ float bf2f(short s) {
  union { unsigned u; float f; } v; v.u = ((unsigned)(unsigned short)s) << 16;
  return v.f;
}

#define GLOBAL_AS(p) ((const __attribute__((address_space(1))) void*)(p))
#define LDS_AS(p)    ((__attribute__((address_space(3))) void*)(p))

// ---------------------------------------------------------------------------
// Batched weight transpose+bf16: 12 descriptors (each a 512-row K-chunk).
struct WD { const float* W; short* Wt; int ldt; int koff; int Nn; };
struct WD12 { WD d[12]; };

__global__ void wconv12_kernel(WD12 ds) {
  __shared__ float tile[32][33];
  const WD dd = ds.d[blockIdx.z];
  int kb = blockIdx.x * 32, nb = blockIdx.y * 32;
  if (nb >= dd.Nn) return;
  int tx = threadIdx.x & 31, ty = threadIdx.x >> 5;
#pragma unroll
  for (int j = 0; j < 4; ++j) {
    int k = kb + ty + 8 * j;
    tile[ty + 8 * j][tx] = dd.W[(size_t)k * dd.Nn + nb + tx];
  }
  __syncthreads();
#pragma unroll
  for (int j = 0; j < 4; ++j) {
    int n = nb + ty + 8 * j;
    dd.Wt[(size_t)n * dd.ldt + dd.koff + kb + tx] = f2bf(tile[tx][ty + 8 * j]);
  }
}

// fp32 -> bf16 flat convert (8 elems/thread)
__global__ void conv_kernel(const float* __restrict__ in, short* __restrict__ outp, int n8) {
  int i = blockIdx.x * 256 + threadIdx.x;
  if (i < n8) {
    float4 a = ((const float4*)in)[i * 2];
    float4 b = ((const float4*)in)[i * 2 + 1];
    short4 o1; o1.x = f2bf(a.x); o1.y = f2bf(a.y); o1.z = f2bf(a.z); o1.w = f2bf(a.w);
    short4 o2; o2.x = f2bf(b.x); o2.y = f2bf(b.y); o2.z = f2bf(b.z); o2.w = f2bf(b.w);
    ((short4*)outp)[i * 2] = o1;
    ((short4*)outp)[i * 2 + 1] = o2;
  }
}

// ---------------------------------------------------------------------------
__global__ void zero3_kernel(int* a, int na, int* b, int nb2, float* c, int nc) {
  int i = blockIdx.x * 256 + threadIdx.x;
  if (i < na) a[i] = 0;
  if (i < nb2) b[i] = 0;
  if (i < nc) c[i] = 0.f;
}

// ---------------------------------------------------------------------------
// CSR build, all 3 layers.
struct L3s { const int* ei[3]; int E[3]; int dbase[3]; int ebase[3]; };

__global__ void deg_all_kernel(L3s L, int* __restrict__ deg) {
  int g = blockIdx.x * 256 + threadIdx.x;
  int l = 0, e = g;
  while (l < 3 && e >= L.E[l]) { e -= L.E[l]; ++l; }
  if (l >= 3) return;
  int d = L.ei[l][L.E[l] + e];
  atomicAdd(&deg[L.dbase[l] + d], 1);
}

// one block (256 thr) per layer; layer size passed in Ln.E[l]
__global__ void scan_all_kernel(L3s Ln, const int* __restrict__ deg, int* __restrict__ offs) {
  __shared__ int sums[257];
  int l = blockIdx.x;
  int n = Ln.E[l];
  const int* dg = deg + Ln.dbase[l];
  int* of = offs + Ln.dbase[l];
  int t = threadIdx.x;
  int per = (n + 255) / 256;
  int b = t * per, e = min(b + per, n);
  int s = 0;
  for (int i = b; i < e; ++i) s += dg[i];
  sums[t] = s;
  __syncthreads();
  if (t == 0) {
    int acc = 0;
    for (int i = 0; i < 256; ++i) { int v = sums[i]; sums[i] = acc; acc += v; }
    sums[256] = acc;
  }
  __syncthreads();
  int acc = sums[t];
  for (int i = b; i < e; ++i) { of[i] = acc; acc += dg[i]; }
  if (t == 255) of[n] = sums[256];
}

__global__ void fill_all_kernel(L3s L, const int* __restrict__ offs,
                                int* __restrict__ cursor, int* __restrict__ csr) {
  int g = blockIdx.x * 256 + threadIdx.x;
  int l = 0, e = g;
  while (l < 3 && e >= L.E[l]) { e -= L.E[l]; ++l; }
  if (l >= 3) return;
  int d = L.ei[l][L.E[l] + e];
  int p = atomicAdd(&cursor[L.dbase[l] + d], 1);
  csr[L.ebase[l] + offs[L.dbase[l] + d] + p] = L.ei[l][e];
}

// ---------------------------------------------------------------------------
// Gather aggregation + fused A build, wave-per-node (4 nodes / 256-thr block).
__global__ void aggregate_kernel(const short* __restrict__ xb, const int* __restrict__ csr,
                                 const int* __restrict__ offs, short* __restrict__ A,
                                 int n_dst) {
  int node = blockIdx.x * 4 + (threadIdx.x >> 6);
  if (node >= n_dst) return;
  int lane = threadIdx.x & 63;
  const short* xp = xb + lane * 8;
  int s0 = offs[node], s1 = offs[node + 1];
  float a[8];
#pragma unroll
  for (int j = 0; j < 8; ++j) a[j] = 0.f;
  int e = s0;
  for (; e + 1 < s1; e += 2) {
    bf16x8 v0 = *(const bf16x8*)(xp + (size_t)csr[e] * 512);
    bf16x8 v1 = *(const bf16x8*)(xp + (size_t)csr[e + 1] * 512);
#pragma unroll
    for (int j = 0; j < 8; ++j) a[j] += bf2f(v0[j]) + bf2f(v1[j]);
  }
  if (e < s1) {
    bf16x8 v0 = *(const bf16x8*)(xp + (size_t)csr[e] * 512);
#pragma unroll
    for (int j = 0; j < 8; ++j) a[j] += bf2f(v0[j]);
  }
  float inv = (s1 > s0) ? 1.0f / (float)(s1 - s0) : 0.0f;
  bf16x8 o;
#pragma unroll
  for (int j = 0; j < 8; ++j) o[j] = f2bf(a[j] * inv);
  *(bf16x8*)(A + (size_t)node * 1024 + lane * 8) = o;
  *(bf16x8*)(A + (size_t)node * 1024 + 512 + lane * 8) =
      *(const bf16x8*)(xp + (size_t)node * 512);
}

// ---------------------------------------------------------------------------
// bf16 MFMA GEMM, BK=64, XOR-swizzled LDS, XCD-grouped 1-D grid.
// id&7 = XCD lane; bn-siblings of a bm-strip share an XCD (A fetched once/XCD).
// LDS [128][64] per operand; k-block c of row r stored at slot c^(r&7).
__global__ __launch_bounds__(256, 2)
void gemm_kernel(const short* __restrict__ A, int lda,
                 const short* __restrict__ Bt, int ldb,
                 float* __restrict__ C, short* __restrict__ Cb, int ldc,
                 int M, int N, int K, const float* __restrict__ bias,
                 float* __restrict__ stats, int gm, int gn) {
  __shared__ short lds[16384];
  short* As = lds;
  short* Bs = lds + 8192;
  const int id = blockIdx.x;
  const int g = id >> 3;
  const int bn = g % gn;
  const int bm = (g / gn) * 8 + (id & 7);
  if (bm >= gm) return;
  const int tid = threadIdx.x;
  const int wid = tid >> 6;
  const int lane = tid & 63;
  const int lm = lane & 15;
  const int quad = lane >> 4;
  const int wr = wid >> 1, wc = wid & 1;
  const int srow = lane >> 3;                       // 0..7 within chunk
  const int kswz = (((lane & 7) ^ srow) << 3);      // swizzled k-offset (elems)

  f32x4 acc[4][4];
#pragma unroll
  for (int i = 0; i < 4; ++i)
#pragma unroll
    for (int j = 0; j < 4; ++j) acc[i][j] = (f32x4)0.f;

  for (int k0 = 0; k0 < K; k0 += 64) {
#pragma unroll
    for (int j = 0; j < 4; ++j) {
      int ch = wid * 4 + j;                         // 16 chunks of 8 rows
      int arow = bm * 128 + ch * 8 + srow;
      arow = arow < M ? arow : M - 1;
      const short* ga = A + (size_t)arow * lda + k0 + kswz;
      __builtin_amdgcn_global_load_lds(GLOBAL_AS(ga), LDS_AS(As + ch * 512), 16, 0, 0);
      int brow = bn * 128 + ch * 8 + srow;
      const short* gb = Bt + (size_t)brow * ldb + k0 + kswz;
      __builtin_amdgcn_global_load_lds(GLOBAL_AS(gb), LDS_AS(Bs + ch * 512), 16, 0, 0);
    }
    __syncthreads();
#pragma unroll
    for (int ks = 0; ks < 2; ++ks) {
      bf16x8 af[4], bfr[4];
      int xo = ((ks * 4 + quad) ^ (lm & 7)) * 8;
#pragma unroll
      for (int mi = 0; mi < 4; ++mi)
        af[mi] = *(const bf16x8*)(As + (wr * 64 + mi * 16 + lm) * 64 + xo);
#pragma unroll
      for (int ni = 0; ni < 4; ++ni)
        bfr[ni] = *(const bf16x8*)(Bs + (wc * 64 + ni * 16 + lm) * 64 + xo);
#pragma unroll
      for (int mi = 0; mi < 4; ++mi)
#pragma unroll
        for (int ni = 0; ni < 4; ++ni)
          acc[mi][ni] = __builtin_amdgcn_mfma_f32_16x16x32_bf16(af[mi], bfr[ni], acc[mi][ni], 0, 0, 0);
    }
    __syncthreads();
  }

#pragma unroll
  for (int mi = 0; mi < 4; ++mi) {
#pragma unroll
    for (int ni = 0; ni < 4; ++ni) {
      int gcol = bn * 128 + wc * 64 + ni * 16 + lm;
      float bv = bias ? bias[gcol] : 0.f;
#pragma unroll
      for (int r2 = 0; r2 < 4; ++r2) {
        int grow = bm * 128 + wr * 64 + mi * 16 + quad * 4 + r2;
        if (grow < M) {
          float val = acc[mi][ni][r2] + bv;
          if (Cb) Cb[(size_t)grow * ldc + gcol] = f2bf(val);
          else    C[(size_t)grow * ldc + gcol] = val;
        }
      }
    }
  }

  if (stats) {
    float* s1 = (float*)lds;
    float* s2 = s1 + 128;
    if (tid < 128) { s1[tid] = 0.f; s2[tid] = 0.f; }
    __syncthreads();
#pragma unroll
    for (int ni = 0; ni < 4; ++ni) {
      int cloc = wc * 64 + ni * 16 + lm;
      float p1 = 0.f, p2 = 0.f;
#pragma unroll
      for (int mi = 0; mi < 4; ++mi)
#pragma unroll
        for (int r2 = 0; r2 < 4; ++r2) {
          int grow = bm * 128 + wr * 64 + mi * 16 + quad * 4 + r2;
          if (grow < M) {
            float v = acc[mi][ni][r2];
            p1 += v; p2 += v * v;
          }
        }
      atomicAdd(&s1[cloc], p1);
      atomicAdd(&s2[cloc], p2);
    }
    __syncthreads();
    if (tid < 128) {
      int gcol = bn * 128 + tid;
      atomicAdd(&stats[gcol], s1[tid]);
      atomicAdd(&stats[512 + gcol], s2[tid]);
    }
  }
}

// ---------------------------------------------------------------------------
// Head GEMM-1: A staged from 4 bf16 x-buffers (concat along K), same scheme.
__global__ __launch_bounds__(256, 2)
void gemm4_kernel(const short* __restrict__ p0, const short* __restrict__ p1,
                  const short* __restrict__ p2, const short* __restrict__ p3,
                  const short* __restrict__ Bt, int ldb,
                  short* __restrict__ Cb, int ldc,
                  int M, int N, const float* __restrict__ bias, int gm, int gn) {
  const int K = 2048;
  __shared__ short lds[16384];
  short* As = lds;
  short* Bs = lds + 8192;
  const int id = blockIdx.x;
  const int g = id >> 3;
  const int bn = g % gn;
  const int bm = (g / gn) * 8 + (id & 7);
  if (bm >= gm) return;
  const int tid = threadIdx.x;
  const int wid = tid >> 6;
  const int lane = tid & 63;
  const int lm = lane & 15;
  const int quad = lane >> 4;
  const int wr = wid >> 1, wc = wid & 1;
  const int srow = lane >> 3;
  const int kswz = (((lane & 7) ^ srow) << 3);

  f32x4 acc[4][4];
#pragma unroll
  for (int i = 0; i < 4; ++i)
#pragma unroll
    for (int j = 0; j < 4; ++j) acc[i][j] = (f32x4)0.f;

  for (int k0 = 0; k0 < K; k0 += 64) {
    const short* Asrc = (k0 < 512) ? p0 : (k0 < 1024) ? p1 : (k0 < 1536) ? p2 : p3;
    int kloc = k0 & 511;
#pragma unroll
    for (int j = 0; j < 4; ++j) {
      int ch = wid * 4 + j;
      int arow = bm * 128 + ch * 8 + srow;
      arow = arow < M ? arow : M - 1;
      const short* ga = Asrc + (size_t)arow * 512 + kloc + kswz;
      __builtin_amdgcn_global_load_lds(GLOBAL_AS(ga), LDS_AS(As + ch * 512), 16, 0, 0);
      int brow = bn * 128 + ch * 8 + srow;
      const short* gb = Bt + (size_t)brow * ldb + k0 + kswz;
      __builtin_amdgcn_global_load_lds(GLOBAL_AS(gb), LDS_AS(Bs + ch * 512), 16, 0, 0);
    }
    __syncthreads();
#pragma unroll
    for (int ks = 0; ks < 2; ++ks) {
      bf16x8 af[4], bfr[4];
      int xo = ((ks * 4 + quad) ^ (lm & 7)) * 8;
#pragma unroll
      for (int mi = 0; mi < 4; ++mi)
        af[mi] = *(const bf16x8*)(As + (wr * 64 + mi * 16 + lm) * 64 + xo);
#pragma unroll
      for (int ni = 0; ni < 4; ++ni)
        bfr[ni] = *(const bf16x8*)(Bs + (wc * 64 + ni * 16 + lm) * 64 + xo);
#pragma unroll
      for (int mi = 0; mi < 4; ++mi)
#pragma unroll
        for (int ni = 0; ni < 4; ++ni)
          acc[mi][ni] = __builtin_amdgcn_mfma_f32_16x16x32_bf16(af[mi], bfr[ni], acc[mi][ni], 0, 0, 0);
    }
    __syncthreads();
  }

#pragma unroll
  for (int mi = 0; mi < 4; ++mi) {
#pragma unroll
    for (int ni = 0; ni < 4; ++ni) {
      int gcol = bn * 128 + wc * 64 + ni * 16 + lm;
      float bv = bias[gcol];
#pragma unroll
      for (int r2 = 0; r2 < 4; ++r2) {
        int grow = bm * 128 + wr * 64 + mi * 16 + quad * 4 + r2;
        if (grow < M) Cb[(size_t)grow * ldc + gcol] = f2bf(acc[mi][ni][r2] + bv);
      }
    }
  }
}

// ---------------------------------------------------------------------------
// x_out(bf16) = leaky(BN(h_bf16; stats)) + (rbuf_bf16 + res_b | xdst_bf16).
__global__ void apply_kernel(const short* __restrict__ h, const float* __restrict__ stats,
                             const float* __restrict__ g, const float* __restrict__ b,
                             const short* __restrict__ r, const float* __restrict__ res_b,
                             const short* __restrict__ xdst, short* __restrict__ outp,
                             int n, float inv_n) {
  int i = blockIdx.x;
  int c = threadIdx.x * 4;
  short4 hb = *(const short4*)(h + (size_t)i * 512 + c);
  float4 s1 = *(const float4*)(stats + c);
  float4 s2 = *(const float4*)(stats + 512 + c);
  float4 gv = *(const float4*)(g + c);
  float4 bv = *(const float4*)(b + c);
  float mux = s1.x * inv_n, muy = s1.y * inv_n, muz = s1.z * inv_n, muw = s1.w * inv_n;
  float rsx = rsqrtf(s2.x * inv_n - mux * mux + 1e-5f);
  float rsy = rsqrtf(s2.y * inv_n - muy * muy + 1e-5f);
  float rsz = rsqrtf(s2.z * inv_n - muz * muz + 1e-5f);
  float rsw = rsqrtf(s2.w * inv_n - muw * muw + 1e-5f);
  float4 o;
  o.x = (bf2f(hb.x) - mux) * rsx * gv.x + bv.x;
  o.y = (bf2f(hb.y) - muy) * rsy * gv.y + bv.y;
  o.z = (bf2f(hb.z) - muz) * rsz * gv.z + bv.z;
  o.w = (bf2f(hb.w) - muw) * rsw * gv.w + bv.w;
  o.x = o.x >= 0.f ? o.x : 0.01f * o.x;
  o.y = o.y >= 0.f ? o.y : 0.01f * o.y;
  o.z = o.z >= 0.f ? o.z : 0.01f * o.z;
  o.w = o.w >= 0.f ? o.w : 0.01f * o.w;
  if (r) {
    short4 rv = *(const short4*)(r + (size_t)i * 512 + c);
    float4 rb = *(const float4*)(res_b + c);
    o.x += bf2f(rv.x) + rb.x; o.y += bf2f(rv.y) + rb.y;
    o.z += bf2f(rv.z) + rb.z; o.w += bf2f(rv.w) + rb.w;
  } else {
    short4 xv = *(const short4*)(xdst + (size_t)i * 512 + c);
    o.x += bf2f(xv.x); o.y += bf2f(xv.y); o.z += bf2f(xv.z); o.w += bf2f(xv.w);
  }
  short4 ov;
  ov.x = f2bf(o.x); ov.y = f2bf(o.y); ov.z = f2bf(o.z); ov.w = f2bf(o.w);
  *(short4*)(outp + (size_t)i * 512 + c) = ov;
}

// ---------------------------------------------------------------------------
__global__ void lsm_kernel(const float* __restrict__ z, float* __restrict__ outp) {
  __shared__ float redm[4], reds[4];
  int row = blockIdx.x, t = threadIdx.x;
  float v = z[(size_t)row * 256 + t];
  float m = v;
#pragma unroll
  for (int o = 32; o >= 1; o >>= 1) m = fmaxf(m, __shfl_down(m, o, 64));
  if ((t & 63) == 0) redm[t >> 6] = m;
  __syncthreads();
  m = fmaxf(fmaxf(redm[0], redm[1]), fmaxf(redm[2], redm[3]));
  float e = __expf(v - m);
  float s = e;
#pragma unroll
  for (int o = 32; o >= 1; o >>= 1) s += __shfl_down(s, o, 64);
  if ((t & 63) == 0) reds[t >> 6] = s;
  __syncthreads();
  s = reds[0] + reds[1] + reds[2] + reds[3];
  outp[(size_t)row * 256 + t] = v - m - __logf(s);
}

// ---------------------------------------------------------------------------
extern "C" void kernel_launch(void* const* d_in, const int* in_sizes, int n_in,
                              void* d_out, int out_size, void* d_ws, size_t ws_size,
                              hipStream_t stream) {
  const float* x0 = (const float*)d_in[0];
  const int* eis[3] = {(const int*)d_in[1], (const int*)d_in[2], (const int*)d_in[3]};
  const float* Wl[3] = {(const float*)d_in[4], (const float*)d_in[8], (const float*)d_in[12]};
  const float* Wr[3] = {(const float*)d_in[5], (const float*)d_in[9], (const float*)d_in[13]};
  const float* gg[3] = {(const float*)d_in[6], (const float*)d_in[10], (const float*)d_in[14]};
  const float* bb[3] = {(const float*)d_in[7], (const float*)d_in[11], (const float*)d_in[15]};
  const float* res_W = (const float*)d_in[16];
  const float* res_b = (const float*)d_in[17];
  const float* mlp_W1 = (const float*)d_in[18];
  const float* mlp_b1 = (const float*)d_in[19];
  const float* mlp_W2 = (const float*)d_in[20];
  const float* mlp_b2 = (const float*)d_in[21];
  float* out = (float*)d_out;

  const int Ns[4] = {60000, 30000, 15000, 8000};
  int Es[3];
  for (int l = 0; l < 3; ++l) Es[l] = in_sizes[1 + l] / 2;
  int Etot = Es[0] + Es[1] + Es[2];

  char* ws = (char*)d_ws;
  size_t off = 0;
  auto alloc = [&](size_t bytes) { size_t r = off; off += (bytes + 255) & ~(size_t)255; return r; };
  short* Bt[3];
  Bt[0] = (short*)(ws + alloc(512 * 1024 * 2));
  Bt[1] = (short*)(ws + alloc(512 * 1024 * 2));
  Bt[2] = (short*)(ws + alloc(512 * 1024 * 2));
  short* Rt = (short*)(ws + alloc(512 * 512 * 2));
  short* W1t = (short*)(ws + alloc(512 * 2048 * 2));
  short* W2t = (short*)(ws + alloc(256 * 512 * 2));
  const int dbase[3] = {0, 30001, 45002};
  const int ndeg = 53003;
  int ebase[3] = {0, Es[0], Es[0] + Es[1]};
  int* deg3 = (int*)(ws + alloc((size_t)ndeg * 4));
  int* offs3 = (int*)(ws + alloc((size_t)ndeg * 4));
  int* cursor3 = (int*)(ws + alloc((size_t)ndeg * 4));
  int* csr3 = (int*)(ws + alloc((size_t)Etot * 4));
  float* stats3 = (float*)(ws + alloc(3 * 1024 * 4));
  short* xb0 = (short*)(ws + alloc((size_t)60000 * 512 * 2));
  short* x1b = (short*)(ws + alloc((size_t)30000 * 512 * 2));
  short* x2b = (short*)(ws + alloc((size_t)15000 * 512 * 2));
  short* x3b = (short*)(ws + alloc((size_t)8000 * 512 * 2));
  short* Abuf = (short*)(ws + alloc((size_t)30000 * 1024 * 2));
  short* h = (short*)(ws + alloc((size_t)30000 * 512 * 2));
  size_t scr_off = alloc((size_t)30000 * 512 * 2);
  short* rbuf = (short*)(ws + scr_off);
  short* z1b = (short*)(ws + scr_off);
  float* z2 = (float*)(ws + alloc((size_t)8000 * 256 * 4));

  // ---- weight prep: one batched dispatch + x0 conversion ----
  WD12 wd;
  wd.d[0] = {Wl[0], Bt[0], 1024, 0, 512};
  wd.d[1] = {Wr[0], Bt[0], 1024, 512, 512};
  wd.d[2] = {Wl[1], Bt[1], 1024, 0, 512};
  wd.d[3] = {Wr[1], Bt[1], 1024, 512, 512};
  wd.d[4] = {Wl[2], Bt[2], 1024, 0, 512};
  wd.d[5] = {Wr[2], Bt[2], 1024, 512, 512};
  wd.d[6] = {res_W, Rt, 512, 0, 512};
  wd.d[7] = {mlp_W1 + 0 * 512 * 512, W1t, 2048, 0, 512};
  wd.d[8] = {mlp_W1 + 1 * 512 * 512, W1t, 2048, 512, 512};
  wd.d[9] = {mlp_W1 + 2 * 512 * 512, W1t, 2048, 1024, 512};
  wd.d[10] = {mlp_W1 + 3 * 512 * 512, W1t, 2048, 1536, 512};
  wd.d[11] = {mlp_W2, W2t, 512, 0, 256};
  wconv12_kernel<<<dim3(16, 16, 12), 256, 0, stream>>>(wd);
  conv_kernel<<<dim3((60000 * 512 / 8 + 255) / 256), 256, 0, stream>>>(x0, xb0, 60000 * 512 / 8);

  // ---- CSR build: 4 dispatches for all 3 layers ----
  L3s L;
  for (int l = 0; l < 3; ++l) {
    L.ei[l] = eis[l]; L.E[l] = Es[l]; L.dbase[l] = dbase[l]; L.ebase[l] = ebase[l];
  }
  zero3_kernel<<<dim3((ndeg + 255) / 256), 256, 0, stream>>>(deg3, ndeg, cursor3, ndeg,
                                                             stats3, 3 * 1024);
  deg_all_kernel<<<dim3((Etot + 255) / 256), 256, 0, stream>>>(L, deg3);
  L3s Ln = L;
  Ln.E[0] = Ns[1]; Ln.E[1] = Ns[2]; Ln.E[2] = Ns[3];
  scan_all_kernel<<<dim3(3), 256, 0, stream>>>(Ln, deg3, offs3);
  fill_all_kernel<<<dim3((Etot + 255) / 256), 256, 0, stream>>>(L, offs3, cursor3, csr3);

  const short* xin[3] = {xb0, x1b, x2b};
  short* xout[3] = {x1b, x2b, x3b};

  auto gblocks = [](int gm, int gn) { return ((gm + 7) / 8) * 8 * gn; };

  for (int l = 0; l < 3; ++l) {
    int n_dst = Ns[l + 1];
    float* stats = stats3 + l * 1024;
    aggregate_kernel<<<dim3((n_dst + 3) / 4), 256, 0, stream>>>(
        xin[l], csr3 + ebase[l], offs3 + dbase[l], Abuf, n_dst);
    int gm = (n_dst + 127) / 128;
    gemm_kernel<<<dim3(gblocks(gm, 4)), 256, 0, stream>>>(
        Abuf, 1024, Bt[l], 1024, nullptr, h, 512, n_dst, 512, 1024, nullptr, stats, gm, 4);
    if (l == 0)
      gemm_kernel<<<dim3(gblocks(gm, 4)), 256, 0, stream>>>(
          Abuf + 512, 1024, Rt, 512, nullptr, rbuf, 512, n_dst, 512, 512, nullptr, nullptr, gm, 4);
    apply_kernel<<<dim3(n_dst), 128, 0, stream>>>(h, stats, gg[l], bb[l],
                                                  l == 0 ? rbuf : nullptr, res_b,
                                                  xin[l], xout[l], n_dst, 1.0f / n_dst);
  }

  // ---- head ----
  {
    int gm = (8000 + 127) / 128;  // 63
    gemm4_kernel<<<dim3(gblocks(gm, 4)), 256, 0, stream>>>(
        xb0, x1b, x2b, x3b, W1t, 2048, z1b, 512, 8000, 512, mlp_b1, gm, 4);
    gemm_kernel<<<dim3(gblocks(gm, 2)), 256, 0, stream>>>(
        z1b, 512, W2t, 512, z2, nullptr, 256, 8000, 256, 512, mlp_b2, nullptr, gm, 2);
  }
  lsm_kernel<<<dim3(8000), 256, 0, stream>>>(z2, out);
}